// Round 5
// baseline (760.111 us; speedup 1.0000x reference)
//
#include <hip/hip_runtime.h>
#include <hip/hip_bf16.h>
#include <stdint.h>
#include <math.h>

#define B_   2
#define L_   3072
#define K_   48
#define FDIM 416
#define NOUT 128

__device__ const int PAIR_A[24] = {0,2,3,4,1,1,1,1,0,0,0,4,4,3,0,2,3,4,2,3,4,2,3,2};
__device__ const int PAIR_B[24] = {0,2,3,4,0,2,3,4,2,3,4,2,3,2,1,1,1,1,0,0,0,4,4,3};

__device__ __forceinline__ unsigned short f2bf(float x) {
    unsigned int u = __float_as_uint(x);
    unsigned int r = (u + 0x7FFFu + ((u >> 16) & 1u)) >> 16;
    return (unsigned short)r;
}
__device__ __forceinline__ float bf2f(unsigned short s) {
    return __uint_as_float(((unsigned int)s) << 16);
}

// ---------------- kernel A: build 5-atom frames + compact Ca ----------------
__global__ __launch_bounds__(256) void k_atoms(const float* __restrict__ X,
                                               float* __restrict__ atoms,
                                               float* __restrict__ CaA)
{
    int row = blockIdx.x * 256 + threadIdx.x;
    if (row >= B_ * L_) return;
    const float* x = X + row * 12;
    float nx = x[0], ny = x[1], nz = x[2];
    float cax = x[3], cay = x[4], caz = x[5];
    float cx = x[6], cy = x[7], cz = x[8];
    float ox = x[9], oy = x[10], oz = x[11];
    float bx = cax - nx, by = cay - ny, bz = caz - nz;   // bvec = Ca - N
    float vx = cx - cax, vy = cy - cay, vz = cz - caz;   // cvec = C - Ca
    float axv = by * vz - bz * vy;                       // avec = cross(b, c)
    float ayv = bz * vx - bx * vz;
    float azv = bx * vy - by * vx;
    float cbx = -0.58273431f * axv + 0.56802827f * bx - 0.54067466f * vx + cax;
    float cby = -0.58273431f * ayv + 0.56802827f * by - 0.54067466f * vy + cay;
    float cbz = -0.58273431f * azv + 0.56802827f * bz - 0.54067466f * vz + caz;
    float* A = atoms + row * 15;
    A[0] = nx;  A[1] = ny;  A[2] = nz;     // N
    A[3] = cax; A[4] = cay; A[5] = caz;    // Ca
    A[6] = cx;  A[7] = cy;  A[8] = cz;     // C
    A[9] = ox;  A[10] = oy; A[11] = oz;    // O
    A[12] = cbx; A[13] = cby; A[14] = cbz; // Cb
    CaA[row * 3 + 0] = cax;
    CaA[row * 3 + 1] = cay;
    CaA[row * 3 + 2] = caz;
}

// ---- kernel B: per-row top-48. Distances in f64 (exact squares, one rounding
// ---- per add, correctly-rounded sqrt), CAST TO F32, then stable tie->lower.
// ---- This reproduces a numpy-f64 reference presented in f32 bit-exactly.
__global__ __launch_bounds__(256) void k_topk(const float* __restrict__ CaA,
                                              const float* __restrict__ mask,
                                              int* __restrict__ eidx,
                                              float* __restrict__ dnb,
                                              float* __restrict__ out_eidx_f)
{
    const int row = blockIdx.x;
    const int b = row / L_;
    const int tid = threadIdx.x;

    const double cax = (double)CaA[row * 3 + 0];
    const double cay = (double)CaA[row * 3 + 1];
    const double caz = (double)CaA[row * 3 + 2];
    const double mi = (double)mask[row];
    const float* Cb = CaA + (size_t)b * L_ * 3;
    const float* mb = mask + (size_t)b * L_;

    double d[12];
    double m2a[12];
    double dmax = 0.0;
    #pragma unroll
    for (int m = 0; m < 12; ++m) {
        int j = tid + 256 * m;
        double dx = cax - (double)Cb[j * 3 + 0];   // exact (f32 diffs in f64)
        double dy = cay - (double)Cb[j * 3 + 1];
        double dz = caz - (double)Cb[j * 3 + 2];
        // squares exact in f64; sum left-to-right, one rounding per add
        double s = dx * dx;
        s = s + dy * dy;
        s = s + dz * dz;
        s = s + 1e-6;
        double dist = sqrt(s);                     // correctly rounded f64
        double m2 = mi * (double)mb[j];
        double D = m2 * dist;
        d[m] = D;
        m2a[m] = m2;
        dmax = fmax(dmax, D);
    }
    // block all-reduce max (f64) for the mask adjustment (identity when mask=1)
    #pragma unroll
    for (int off = 32; off >= 1; off >>= 1)
        dmax = fmax(dmax, __shfl_xor(dmax, off));
    __shared__ double smax[4];
    __shared__ unsigned long long swin[4];
    const int wv = tid >> 6;
    if ((tid & 63) == 0) smax[wv] = dmax;
    __syncthreads();
    dmax = fmax(fmax(smax[0], smax[1]), fmax(smax[2], smax[3]));

    // f32-cast keys (correctly-rounded f32 of the f64 distance)
    float df[12];
    #pragma unroll
    for (int m = 0; m < 12; ++m)
        df[m] = (float)(d[m] + (1.0 - m2a[m]) * dmax);
    __syncthreads();

    for (int k = 0; k < K_; ++k) {
        // key = (f32_bits << 32) | j : min-key => smallest dist, tie -> lower j
        unsigned long long best = ~0ull;
        #pragma unroll
        for (int m = 0; m < 12; ++m) {
            unsigned long long key =
                ((unsigned long long)__float_as_uint(df[m]) << 32) | (unsigned)(tid + 256 * m);
            best = (key < best) ? key : best;
        }
        #pragma unroll
        for (int off = 32; off >= 1; off >>= 1) {
            unsigned long long o = __shfl_xor(best, off);
            best = (o < best) ? o : best;
        }
        if ((tid & 63) == 0) swin[wv] = best;
        __syncthreads();
        {
            unsigned long long b0 = swin[0] < swin[1] ? swin[0] : swin[1];
            unsigned long long b1 = swin[2] < swin[3] ? swin[2] : swin[3];
            best = b0 < b1 ? b0 : b1;
        }
        int jw = (int)(unsigned)(best & 0xffffffffu);
        if ((jw & 255) == tid) df[jw >> 8] = __builtin_inff();
        if (tid == 0) {
            eidx[row * K_ + k] = jw;
            dnb[row * K_ + k] = __uint_as_float((unsigned)(best >> 32));
            out_eidx_f[row * K_ + k] = (float)jw;
        }
        __syncthreads();
    }
}

// ---------------- kernel C: edge features -> 416x128 matvec -> LayerNorm ----------------
__global__ __launch_bounds__(256) void k_edge(const float* __restrict__ atoms,
                                              const int* __restrict__ eidx,
                                              const float* __restrict__ dnb,
                                              const int* __restrict__ Ridx,
                                              const int* __restrict__ chain,
                                              const float* __restrict__ posW,
                                              const float* __restrict__ posb,
                                              const float* __restrict__ edgeW,
                                              const float* __restrict__ gamma,
                                              const float* __restrict__ beta,
                                              float* __restrict__ Eout)
{
    __shared__ __align__(16) unsigned short F[K_ * FDIM]; // 39,936 B (bf16 features)
    __shared__ float D25[K_ * 25];                        // 4,800 B
    __shared__ int sE[K_];
    __shared__ float sDnb[K_];

    const int row = blockIdx.x;
    const int b = row / L_;
    const int tid = threadIdx.x;

    if (tid < K_) {
        sE[tid] = eidx[row * K_ + tid];
        sDnb[tid] = dnb[row * K_ + tid];
    }
    __syncthreads();

    // 25 distances per edge: dd=0 -> D_neighbors, dd=1..24 -> pair dd-1
    for (int t = tid; t < K_ * 25; t += 256) {
        int k = t / 25, dd = t % 25;
        float D;
        if (dd == 0) {
            D = sDnb[k];
        } else {
            int j = sE[k];
            int ai = PAIR_A[dd - 1], bi = PAIR_B[dd - 1];
            const float* pi = atoms + ((size_t)row * 15 + ai * 3);
            const float* pj = atoms + (((size_t)b * L_ + j) * 15 + bi * 3);
            float dx = pi[0] - pj[0];
            float dy = pi[1] - pj[1];
            float dz = pi[2] - pj[2];
            float s = dx * dx;
            s += dy * dy;
            s += dz * dz;
            D = sqrtf(s + 1e-6f);
        }
        D25[t] = D;
    }

    // positional features: F[k][0..15]
    {
        int Ri = Ridx[row];
        int ci = chain[row];
        for (int t = tid; t < K_ * 16; t += 256) {
            int k = t >> 4, r = t & 15;
            int j = sE[k];
            int off = Ri - Ridx[b * L_ + j];
            int ch = (ci == chain[b * L_ + j]) ? 1 : 0;
            int dpos = ch ? min(max(off + 32, 0), 64) : 65;
            float v = posW[dpos * 16 + r] + posb[r];
            F[k * FDIM + r] = f2bf(v);
        }
    }
    __syncthreads();

    // RBF: F[k][16 + dd*16 + r] = exp(-(((D - mu_r)/1.25)^2))
    for (int t = tid; t < K_ * 400; t += 256) {
        int k = t / 400, rem = t % 400;
        int dd = rem >> 4, r = rem & 15;
        float D = D25[k * 25 + dd];
        float mu = 2.0f + 1.33333333333333f * (float)r;
        float z = (D - mu) * 0.8f;
        F[k * FDIM + 16 + rem] = f2bf(__expf(-z * z));
    }
    __syncthreads();

    // GEMM: 48x416 (bf16 LDS) @ 416x128 (f32 global) -> fp32 acc
    const int tx = tid & 31;
    const int ty = tid >> 5;
    float acc[6][4];
    #pragma unroll
    for (int p = 0; p < 6; ++p)
        #pragma unroll
        for (int q = 0; q < 4; ++q)
            acc[p][q] = 0.0f;

    for (int c = 0; c < FDIM; c += 4) {
        float w[4][4];
        #pragma unroll
        for (int cc = 0; cc < 4; ++cc)
            #pragma unroll
            for (int q = 0; q < 4; ++q)
                w[cc][q] = edgeW[(c + cc) * 128 + tx + 32 * q];
        #pragma unroll
        for (int p = 0; p < 6; ++p) {
            int k = ty + 8 * p;
            uint2 fv = *(const uint2*)(F + k * FDIM + c);
            float f0 = bf2f((unsigned short)(fv.x & 0xffffu));
            float f1 = bf2f((unsigned short)(fv.x >> 16));
            float f2v = bf2f((unsigned short)(fv.y & 0xffffu));
            float f3 = bf2f((unsigned short)(fv.y >> 16));
            #pragma unroll
            for (int q = 0; q < 4; ++q)
                acc[p][q] += f0 * w[0][q] + f1 * w[1][q] + f2v * w[2][q] + f3 * w[3][q];
        }
    }

    float g[4], be[4];
    #pragma unroll
    for (int q = 0; q < 4; ++q) {
        g[q] = gamma[tx + 32 * q];
        be[q] = beta[tx + 32 * q];
    }

    // LayerNorm over 128 per (row, k): reduce across 32 lanes
    #pragma unroll
    for (int p = 0; p < 6; ++p) {
        int k = ty + 8 * p;
        float s = acc[p][0] + acc[p][1] + acc[p][2] + acc[p][3];
        #pragma unroll
        for (int mo = 16; mo >= 1; mo >>= 1) s += __shfl_xor(s, mo);
        float mu = s * (1.0f / 128.0f);
        float vs = 0.0f;
        #pragma unroll
        for (int q = 0; q < 4; ++q) {
            float dv = acc[p][q] - mu;
            vs += dv * dv;
        }
        #pragma unroll
        for (int mo = 16; mo >= 1; mo >>= 1) vs += __shfl_xor(vs, mo);
        float inv = 1.0f / sqrtf(vs * (1.0f / 128.0f) + 1e-5f);
        float* op = Eout + ((size_t)row * K_ + k) * 128;
        #pragma unroll
        for (int q = 0; q < 4; ++q)
            op[tx + 32 * q] = (acc[p][q] - mu) * inv * g[q] + be[q];
    }
}

extern "C" void kernel_launch(void* const* d_in, const int* in_sizes, int n_in,
                              void* d_out, int out_size, void* d_ws, size_t ws_size,
                              hipStream_t stream) {
    const float* X     = (const float*)d_in[0];
    const float* mask  = (const float*)d_in[1];
    const int*   Ridx  = (const int*)d_in[2];
    const int*   chain = (const int*)d_in[3];
    const float* posW  = (const float*)d_in[4];
    const float* posb  = (const float*)d_in[5];
    const float* edgeW = (const float*)d_in[6];
    const float* gamma = (const float*)d_in[7];
    const float* beta  = (const float*)d_in[8];

    float* out   = (float*)d_out;
    float* Eout  = out;                                      // B*L*K*128 floats
    float* EidxF = out + (size_t)B_ * L_ * K_ * NOUT;        // B*L*K floats (indices as float)

    float* atoms = (float*)d_ws;                             // B*L*15
    float* CaA   = atoms + (size_t)B_ * L_ * 15;             // B*L*3
    int*   eidx  = (int*)(CaA + (size_t)B_ * L_ * 3);        // B*L*K
    float* dnb   = (float*)(eidx + (size_t)B_ * L_ * K_);    // B*L*K

    hipLaunchKernelGGL(k_atoms, dim3((B_ * L_ + 255) / 256), dim3(256), 0, stream,
                       X, atoms, CaA);
    hipLaunchKernelGGL(k_topk, dim3(B_ * L_), dim3(256), 0, stream,
                       CaA, mask, eidx, dnb, EidxF);
    hipLaunchKernelGGL(k_edge, dim3(B_ * L_), dim3(256), 0, stream,
                       atoms, eidx, dnb, Ridx, chain, posW, posb, edgeW, gamma, beta, Eout);
}

// Round 6
// 376.381 us; speedup vs baseline: 2.0195x; 2.0195x over previous
//
#include <hip/hip_runtime.h>
#include <hip/hip_bf16.h>
#include <stdint.h>
#include <math.h>

#define B_   2
#define L_   3072
#define K_   48
#define FDIM 416
#define NOUT 128
#define FRS  424   // F row stride (bf16 elems): 424*2B=848B=212dw, 212%32=20 -> spread banks
#define CRS  132   // C row stride (f32) for LN phase

__device__ const int PAIR_A[24] = {0,2,3,4,1,1,1,1,0,0,0,4,4,3,0,2,3,4,2,3,4,2,3,2};
__device__ const int PAIR_B[24] = {0,2,3,4,0,2,3,4,2,3,4,2,3,2,1,1,1,1,0,0,0,4,4,3};

typedef __attribute__((ext_vector_type(8))) short bf16x8;
typedef __attribute__((ext_vector_type(4))) float f32x4;

__device__ __forceinline__ unsigned short f2bf(float x) {
    unsigned int u = __float_as_uint(x);
    unsigned int r = (u + 0x7FFFu + ((u >> 16) & 1u)) >> 16;
    return (unsigned short)r;
}

// ---------------- kernel W: edgeW (416x128 f32) -> W_t (128x416 bf16) ----------------
__global__ __launch_bounds__(256) void k_prepW(const float* __restrict__ edgeW,
                                               unsigned short* __restrict__ Wt)
{
    int idx = blockIdx.x * 256 + threadIdx.x;
    if (idx >= NOUT * FDIM) return;
    int n = idx / FDIM;
    int k = idx - n * FDIM;
    Wt[idx] = f2bf(edgeW[k * NOUT + n]);
}

// ---------------- kernel A: build 5-atom frames + compact Ca ----------------
__global__ __launch_bounds__(256) void k_atoms(const float* __restrict__ X,
                                               float* __restrict__ atoms,
                                               float* __restrict__ CaA)
{
    int row = blockIdx.x * 256 + threadIdx.x;
    if (row >= B_ * L_) return;
    const float* x = X + row * 12;
    float nx = x[0], ny = x[1], nz = x[2];
    float cax = x[3], cay = x[4], caz = x[5];
    float cx = x[6], cy = x[7], cz = x[8];
    float ox = x[9], oy = x[10], oz = x[11];
    float bx = cax - nx, by = cay - ny, bz = caz - nz;   // bvec = Ca - N
    float vx = cx - cax, vy = cy - cay, vz = cz - caz;   // cvec = C - Ca
    float axv = by * vz - bz * vy;                       // avec = cross(b, c)
    float ayv = bz * vx - bx * vz;
    float azv = bx * vy - by * vx;
    float cbx = -0.58273431f * axv + 0.56802827f * bx - 0.54067466f * vx + cax;
    float cby = -0.58273431f * ayv + 0.56802827f * by - 0.54067466f * vy + cay;
    float cbz = -0.58273431f * azv + 0.56802827f * bz - 0.54067466f * vz + caz;
    float* A = atoms + row * 15;
    A[0] = nx;  A[1] = ny;  A[2] = nz;
    A[3] = cax; A[4] = cay; A[5] = caz;
    A[6] = cx;  A[7] = cy;  A[8] = cz;
    A[9] = ox;  A[10] = oy; A[11] = oz;
    A[12] = cbx; A[13] = cby; A[14] = cbz;
    CaA[row * 3 + 0] = cax;
    CaA[row * 3 + 1] = cay;
    CaA[row * 3 + 2] = caz;
}

// ---- kernel B: per-row top-48. f64 distances cast to f32, stable tie->lower. ----
__global__ __launch_bounds__(256) void k_topk(const float* __restrict__ CaA,
                                              const float* __restrict__ mask,
                                              int* __restrict__ eidx,
                                              float* __restrict__ dnb,
                                              float* __restrict__ out_eidx_f)
{
    const int row = blockIdx.x;
    const int b = row / L_;
    const int tid = threadIdx.x;

    const double cax = (double)CaA[row * 3 + 0];
    const double cay = (double)CaA[row * 3 + 1];
    const double caz = (double)CaA[row * 3 + 2];
    const double mi = (double)mask[row];
    const float* Cb = CaA + (size_t)b * L_ * 3;
    const float* mb = mask + (size_t)b * L_;

    double d[12];
    double m2a[12];
    double dmax = 0.0;
    #pragma unroll
    for (int m = 0; m < 12; ++m) {
        int j = tid + 256 * m;
        double dx = cax - (double)Cb[j * 3 + 0];
        double dy = cay - (double)Cb[j * 3 + 1];
        double dz = caz - (double)Cb[j * 3 + 2];
        double s = dx * dx;
        s = s + dy * dy;
        s = s + dz * dz;
        s = s + 1e-6;
        double dist = sqrt(s);
        double m2 = mi * (double)mb[j];
        double D = m2 * dist;
        d[m] = D;
        m2a[m] = m2;
        dmax = fmax(dmax, D);
    }
    #pragma unroll
    for (int off = 32; off >= 1; off >>= 1)
        dmax = fmax(dmax, __shfl_xor(dmax, off));
    __shared__ double smax[4];
    __shared__ unsigned long long swin[4];
    const int wv = tid >> 6;
    if ((tid & 63) == 0) smax[wv] = dmax;
    __syncthreads();
    dmax = fmax(fmax(smax[0], smax[1]), fmax(smax[2], smax[3]));

    float df[12];
    #pragma unroll
    for (int m = 0; m < 12; ++m)
        df[m] = (float)(d[m] + (1.0 - m2a[m]) * dmax);
    __syncthreads();

    for (int k = 0; k < K_; ++k) {
        unsigned long long best = ~0ull;
        #pragma unroll
        for (int m = 0; m < 12; ++m) {
            unsigned long long key =
                ((unsigned long long)__float_as_uint(df[m]) << 32) | (unsigned)(tid + 256 * m);
            best = (key < best) ? key : best;
        }
        #pragma unroll
        for (int off = 32; off >= 1; off >>= 1) {
            unsigned long long o = __shfl_xor(best, off);
            best = (o < best) ? o : best;
        }
        if ((tid & 63) == 0) swin[wv] = best;
        __syncthreads();
        {
            unsigned long long b0 = swin[0] < swin[1] ? swin[0] : swin[1];
            unsigned long long b1 = swin[2] < swin[3] ? swin[2] : swin[3];
            best = b0 < b1 ? b0 : b1;
        }
        int jw = (int)(unsigned)(best & 0xffffffffu);
        if ((jw & 255) == tid) df[jw >> 8] = __builtin_inff();
        if (tid == 0) {
            eidx[row * K_ + k] = jw;
            dnb[row * K_ + k] = __uint_as_float((unsigned)(best >> 32));
            out_eidx_f[row * K_ + k] = (float)jw;
        }
        __syncthreads();
    }
}

// ---------------- kernel C: features -> MFMA 48x416x128 -> LayerNorm ----------------
__global__ __launch_bounds__(256) void k_edge(const float* __restrict__ atoms,
                                              const int* __restrict__ eidx,
                                              const float* __restrict__ dnb,
                                              const int* __restrict__ Ridx,
                                              const int* __restrict__ chain,
                                              const float* __restrict__ posW,
                                              const float* __restrict__ posb,
                                              const unsigned short* __restrict__ Wt,
                                              const float* __restrict__ gamma,
                                              const float* __restrict__ beta,
                                              float* __restrict__ Eout)
{
    // F (bf16 [48][424], 40704 B) and C (f32 [48][132], 25344 B) share this buffer
    __shared__ __align__(16) unsigned short SMEM[K_ * FRS];
    __shared__ float D25[K_ * 25];
    __shared__ int sE[K_];
    __shared__ float sDnb[K_];

    const int row = blockIdx.x;
    const int b = row / L_;
    const int tid = threadIdx.x;

    if (tid < K_) {
        sE[tid] = eidx[row * K_ + tid];
        sDnb[tid] = dnb[row * K_ + tid];
    }
    __syncthreads();

    unsigned short* F = SMEM;

    // 25 distances per edge
    for (int t = tid; t < K_ * 25; t += 256) {
        int k = t / 25, dd = t - k * 25;
        float D;
        if (dd == 0) {
            D = sDnb[k];
        } else {
            int j = sE[k];
            int ai = PAIR_A[dd - 1], bi = PAIR_B[dd - 1];
            const float* pi = atoms + ((size_t)row * 15 + ai * 3);
            const float* pj = atoms + (((size_t)b * L_ + j) * 15 + bi * 3);
            float dx = pi[0] - pj[0];
            float dy = pi[1] - pj[1];
            float dz = pi[2] - pj[2];
            float s = dx * dx;
            s += dy * dy;
            s += dz * dz;
            D = sqrtf(s + 1e-6f);
        }
        D25[t] = D;
    }

    // positional features: F[k][0..15]
    {
        int Ri = Ridx[row];
        int ci = chain[row];
        for (int t = tid; t < K_ * 16; t += 256) {
            int k = t >> 4, r = t & 15;
            int j = sE[k];
            int off = Ri - Ridx[b * L_ + j];
            int ch = (ci == chain[b * L_ + j]) ? 1 : 0;
            int dpos = ch ? min(max(off + 32, 0), 64) : 65;
            float v = posW[dpos * 16 + r] + posb[r];
            F[k * FRS + r] = f2bf(v);
        }
    }
    __syncthreads();

    // RBF: F[k][16 + dd*16 + r]
    for (int t = tid; t < K_ * 400; t += 256) {
        int k = t / 400, rem = t - k * 400;
        int r = rem & 15;
        float D = D25[k * 25 + (rem >> 4)];
        float mu = 2.0f + 1.33333333333333f * (float)r;
        float z = (D - mu) * 0.8f;
        F[k * FRS + 16 + rem] = f2bf(__expf(-z * z));
    }
    __syncthreads();

    // MFMA GEMM: C[48][128] = F[48][416] @ W[416][128]
    // wave wv handles N-tiles {2*wv, 2*wv+1}; 3 M-tiles; 13 K-steps of 32.
    const int lane = tid & 63;
    const int wv = tid >> 6;
    const int l15 = lane & 15;
    const int lhi = lane >> 4;   // 0..3

    f32x4 acc[3][2];
    #pragma unroll
    for (int mt = 0; mt < 3; ++mt)
        #pragma unroll
        for (int nn = 0; nn < 2; ++nn)
            acc[mt][nn] = (f32x4){0.f, 0.f, 0.f, 0.f};

    #pragma unroll 1
    for (int kt = 0; kt < 13; ++kt) {
        const int k0 = kt * 32 + lhi * 8;
        bf16x8 a[3], bf[2];
        #pragma unroll
        for (int mt = 0; mt < 3; ++mt)
            a[mt] = *(const bf16x8*)(F + (mt * 16 + l15) * FRS + k0);
        #pragma unroll
        for (int nn = 0; nn < 2; ++nn) {
            int n = wv * 32 + nn * 16 + l15;
            bf[nn] = *(const bf16x8*)(Wt + n * FDIM + k0);
        }
        #pragma unroll
        for (int mt = 0; mt < 3; ++mt)
            #pragma unroll
            for (int nn = 0; nn < 2; ++nn)
                acc[mt][nn] = __builtin_amdgcn_mfma_f32_16x16x32_bf16(a[mt], bf[nn], acc[mt][nn], 0, 0, 0);
    }

    // spill C to LDS (f32 [48][132]) -- C/D layout: col=lane&15, row=(lane>>4)*4+reg
    __syncthreads();
    float* C = (float*)SMEM;
    #pragma unroll
    for (int mt = 0; mt < 3; ++mt) {
        #pragma unroll
        for (int nn = 0; nn < 2; ++nn) {
            int r0 = mt * 16 + lhi * 4;
            int col = wv * 32 + nn * 16 + l15;
            #pragma unroll
            for (int r = 0; r < 4; ++r)
                C[(r0 + r) * CRS + col] = acc[mt][nn][r];
        }
    }
    __syncthreads();

    // LayerNorm over 128 per edge row
    const int tx = tid & 31;
    const int ty = tid >> 5;
    float g[4], be[4];
    #pragma unroll
    for (int q = 0; q < 4; ++q) {
        g[q] = gamma[tx + 32 * q];
        be[q] = beta[tx + 32 * q];
    }

    #pragma unroll
    for (int p = 0; p < 6; ++p) {
        int k = ty + 8 * p;
        float v[4];
        #pragma unroll
        for (int q = 0; q < 4; ++q)
            v[q] = C[k * CRS + tx + 32 * q];
        float s = v[0] + v[1] + v[2] + v[3];
        #pragma unroll
        for (int mo = 16; mo >= 1; mo >>= 1) s += __shfl_xor(s, mo);
        float mu = s * (1.0f / 128.0f);
        float vs = 0.0f;
        #pragma unroll
        for (int q = 0; q < 4; ++q) {
            float dv = v[q] - mu;
            vs += dv * dv;
        }
        #pragma unroll
        for (int mo = 16; mo >= 1; mo >>= 1) vs += __shfl_xor(vs, mo);
        float inv = 1.0f / sqrtf(vs * (1.0f / 128.0f) + 1e-5f);
        float* op = Eout + ((size_t)row * K_ + k) * 128;
        #pragma unroll
        for (int q = 0; q < 4; ++q)
            op[tx + 32 * q] = (v[q] - mu) * inv * g[q] + be[q];
    }
}

extern "C" void kernel_launch(void* const* d_in, const int* in_sizes, int n_in,
                              void* d_out, int out_size, void* d_ws, size_t ws_size,
                              hipStream_t stream) {
    const float* X     = (const float*)d_in[0];
    const float* mask  = (const float*)d_in[1];
    const int*   Ridx  = (const int*)d_in[2];
    const int*   chain = (const int*)d_in[3];
    const float* posW  = (const float*)d_in[4];
    const float* posb  = (const float*)d_in[5];
    const float* edgeW = (const float*)d_in[6];
    const float* gamma = (const float*)d_in[7];
    const float* beta  = (const float*)d_in[8];

    float* out   = (float*)d_out;
    float* Eout  = out;                                      // B*L*K*128 floats
    float* EidxF = out + (size_t)B_ * L_ * K_ * NOUT;        // B*L*K floats

    float* atoms = (float*)d_ws;                             // B*L*15
    float* CaA   = atoms + (size_t)B_ * L_ * 15;             // B*L*3
    int*   eidx  = (int*)(CaA + (size_t)B_ * L_ * 3);        // B*L*K
    float* dnb   = (float*)(eidx + (size_t)B_ * L_ * K_);    // B*L*K
    unsigned short* Wt = (unsigned short*)(dnb + (size_t)B_ * L_ * K_);  // 128*416 bf16

    hipLaunchKernelGGL(k_prepW, dim3((NOUT * FDIM + 255) / 256), dim3(256), 0, stream,
                       edgeW, Wt);
    hipLaunchKernelGGL(k_atoms, dim3((B_ * L_ + 255) / 256), dim3(256), 0, stream,
                       X, atoms, CaA);
    hipLaunchKernelGGL(k_topk, dim3(B_ * L_), dim3(256), 0, stream,
                       CaA, mask, eidx, dnb, EidxF);
    hipLaunchKernelGGL(k_edge, dim3(B_ * L_), dim3(256), 0, stream,
                       atoms, eidx, dnb, Ridx, chain, posW, posb, Wt, gamma, beta, Eout);
}

// Round 7
// 351.375 us; speedup vs baseline: 2.1632x; 1.0712x over previous
//
#include <hip/hip_runtime.h>
#include <hip/hip_bf16.h>
#include <stdint.h>
#include <math.h>

#define B_   2
#define L_   3072
#define K_   48
#define FDIM 416
#define NOUT 128
#define FRS  424   // F row stride (bf16 elems)
#define CRS  132   // C row stride (f32) for LN phase

__device__ const int PAIR_A[24] = {0,2,3,4,1,1,1,1,0,0,0,4,4,3,0,2,3,4,2,3,4,2,3,2};
__device__ const int PAIR_B[24] = {0,2,3,4,0,2,3,4,2,3,4,2,3,2,1,1,1,1,0,0,0,4,4,3};

typedef __attribute__((ext_vector_type(8))) short bf16x8;
typedef __attribute__((ext_vector_type(4))) float f32x4;

__device__ __forceinline__ unsigned short f2bf(float x) {
    unsigned int u = __float_as_uint(x);
    unsigned int r = (u + 0x7FFFu + ((u >> 16) & 1u)) >> 16;
    return (unsigned short)r;
}

// ---------------- kernel W: edgeW (416x128 f32) -> W_t (128x416 bf16) ----------------
__global__ __launch_bounds__(256) void k_prepW(const float* __restrict__ edgeW,
                                               unsigned short* __restrict__ Wt)
{
    int idx = blockIdx.x * 256 + threadIdx.x;
    if (idx >= NOUT * FDIM) return;
    int n = idx / FDIM;
    int k = idx - n * FDIM;
    Wt[idx] = f2bf(edgeW[k * NOUT + n]);
}

// ---------------- kernel A: build 5-atom frames + compact Ca ----------------
__global__ __launch_bounds__(256) void k_atoms(const float* __restrict__ X,
                                               float* __restrict__ atoms,
                                               float* __restrict__ CaA)
{
    int row = blockIdx.x * 256 + threadIdx.x;
    if (row >= B_ * L_) return;
    const float* x = X + row * 12;
    float nx = x[0], ny = x[1], nz = x[2];
    float cax = x[3], cay = x[4], caz = x[5];
    float cx = x[6], cy = x[7], cz = x[8];
    float ox = x[9], oy = x[10], oz = x[11];
    float bx = cax - nx, by = cay - ny, bz = caz - nz;
    float vx = cx - cax, vy = cy - cay, vz = cz - caz;
    float axv = by * vz - bz * vy;
    float ayv = bz * vx - bx * vz;
    float azv = bx * vy - by * vx;
    float cbx = -0.58273431f * axv + 0.56802827f * bx - 0.54067466f * vx + cax;
    float cby = -0.58273431f * ayv + 0.56802827f * by - 0.54067466f * vy + cay;
    float cbz = -0.58273431f * azv + 0.56802827f * bz - 0.54067466f * vz + caz;
    float* A = atoms + row * 15;
    A[0] = nx;  A[1] = ny;  A[2] = nz;
    A[3] = cax; A[4] = cay; A[5] = caz;
    A[6] = cx;  A[7] = cy;  A[8] = cz;
    A[9] = ox;  A[10] = oy; A[11] = oz;
    A[12] = cbx; A[13] = cby; A[14] = cbz;
    CaA[row * 3 + 0] = cax;
    CaA[row * 3 + 1] = cay;
    CaA[row * 3 + 2] = caz;
}

// ---- kernel B: per-row top-48. f64 distances cast to f32, stable tie->lower.
// ---- All state in VGPRs (static indexing); cached local min; 1 barrier/iter.
__global__ __launch_bounds__(256) void k_topk(const float* __restrict__ CaA,
                                              const float* __restrict__ mask,
                                              int* __restrict__ eidx,
                                              float* __restrict__ dnb,
                                              float* __restrict__ out_eidx_f)
{
    const int row = blockIdx.x;
    const int b = row / L_;
    const int tid = threadIdx.x;

    const double cax = (double)CaA[row * 3 + 0];
    const double cay = (double)CaA[row * 3 + 1];
    const double caz = (double)CaA[row * 3 + 2];
    const double mi = (double)mask[row];
    const float* Cb = CaA + (size_t)b * L_ * 3;
    const float* mb = mask + (size_t)b * L_;

    double d64[12];
    float m2f[12];
    double dmax = 0.0;
    #pragma unroll
    for (int m = 0; m < 12; ++m) {
        int j = tid + 256 * m;
        double dx = cax - (double)Cb[j * 3 + 0];
        double dy = cay - (double)Cb[j * 3 + 1];
        double dz = caz - (double)Cb[j * 3 + 2];
        double s = dx * dx;
        s = s + dy * dy;
        s = s + dz * dz;
        s = s + 1e-6;
        double dist = sqrt(s);
        double m2 = mi * (double)mb[j];
        double D = m2 * dist;
        d64[m] = D;
        m2f[m] = (float)m2;
        dmax = fmax(dmax, D);
    }
    #pragma unroll
    for (int off = 32; off >= 1; off >>= 1)
        dmax = fmax(dmax, __shfl_xor(dmax, off));
    __shared__ double smax[4];
    __shared__ unsigned long long swin2[2][4];
    const int wv = tid >> 6;
    if ((tid & 63) == 0) smax[wv] = dmax;
    __syncthreads();
    dmax = fmax(fmax(smax[0], smax[1]), fmax(smax[2], smax[3]));

    // packed keys: (f32 bits << 32) | j  -> min-key = smallest dist, tie -> lower j
    unsigned long long keys[12];
    #pragma unroll
    for (int m = 0; m < 12; ++m) {
        float v = (float)(d64[m] + (1.0 - (double)m2f[m]) * dmax);
        keys[m] = ((unsigned long long)__float_as_uint(v) << 32) | (unsigned)(tid + 256 * m);
    }
    unsigned long long lmin = keys[0];
    #pragma unroll
    for (int m = 1; m < 12; ++m) lmin = keys[m] < lmin ? keys[m] : lmin;
    __syncthreads();   // smax read done before swin2 reuse region (separate arrays, but order anyway)

    int buf = 0;
    for (int k = 0; k < K_; ++k) {
        unsigned long long w = lmin;
        #pragma unroll
        for (int off = 32; off >= 1; off >>= 1) {
            unsigned long long o = __shfl_xor(w, off);
            w = o < w ? o : w;
        }
        if ((tid & 63) == 0) swin2[buf][wv] = w;
        __syncthreads();
        unsigned long long b0 = swin2[buf][0] < swin2[buf][1] ? swin2[buf][0] : swin2[buf][1];
        unsigned long long b1 = swin2[buf][2] < swin2[buf][3] ? swin2[buf][2] : swin2[buf][3];
        unsigned long long g = b0 < b1 ? b0 : b1;
        int gj = (int)(unsigned)(g & 0xffffffffu);

        if ((gj & 255) == tid) {
            const int mm = gj >> 8;
            #pragma unroll
            for (int m = 0; m < 12; ++m)
                if (m == mm) keys[m] = ~0ull;
            unsigned long long t = keys[0];
            #pragma unroll
            for (int m = 1; m < 12; ++m) t = keys[m] < t ? keys[m] : t;
            lmin = t;
        }
        if (tid == 0) {
            eidx[row * K_ + k] = gj;
            dnb[row * K_ + k] = __uint_as_float((unsigned)(g >> 32));
            out_eidx_f[row * K_ + k] = (float)gj;
        }
        buf ^= 1;
    }
}

// ---------------- kernel C: features -> MFMA 48x416x128 -> LayerNorm ----------------
__global__ __launch_bounds__(256) void k_edge(const float* __restrict__ atoms,
                                              const int* __restrict__ eidx,
                                              const float* __restrict__ dnb,
                                              const int* __restrict__ Ridx,
                                              const int* __restrict__ chain,
                                              const float* __restrict__ posW,
                                              const float* __restrict__ posb,
                                              const unsigned short* __restrict__ Wt,
                                              const float* __restrict__ gamma,
                                              const float* __restrict__ beta,
                                              float* __restrict__ Eout)
{
    __shared__ __align__(16) unsigned short SMEM[K_ * FRS];
    __shared__ float D25[K_ * 25];
    __shared__ int sE[K_];
    __shared__ float sDnb[K_];

    const int row = blockIdx.x;
    const int b = row / L_;
    const int tid = threadIdx.x;

    if (tid < K_) {
        sE[tid] = eidx[row * K_ + tid];
        sDnb[tid] = dnb[row * K_ + tid];
    }
    __syncthreads();

    unsigned short* F = SMEM;

    for (int t = tid; t < K_ * 25; t += 256) {
        int k = t / 25, dd = t - k * 25;
        float D;
        if (dd == 0) {
            D = sDnb[k];
        } else {
            int j = sE[k];
            int ai = PAIR_A[dd - 1], bi = PAIR_B[dd - 1];
            const float* pi = atoms + ((size_t)row * 15 + ai * 3);
            const float* pj = atoms + (((size_t)b * L_ + j) * 15 + bi * 3);
            float dx = pi[0] - pj[0];
            float dy = pi[1] - pj[1];
            float dz = pi[2] - pj[2];
            float s = dx * dx;
            s += dy * dy;
            s += dz * dz;
            D = sqrtf(s + 1e-6f);
        }
        D25[t] = D;
    }

    {
        int Ri = Ridx[row];
        int ci = chain[row];
        for (int t = tid; t < K_ * 16; t += 256) {
            int k = t >> 4, r = t & 15;
            int j = sE[k];
            int off = Ri - Ridx[b * L_ + j];
            int ch = (ci == chain[b * L_ + j]) ? 1 : 0;
            int dpos = ch ? min(max(off + 32, 0), 64) : 65;
            float v = posW[dpos * 16 + r] + posb[r];
            F[k * FRS + r] = f2bf(v);
        }
    }
    __syncthreads();

    for (int t = tid; t < K_ * 400; t += 256) {
        int k = t / 400, rem = t - k * 400;
        int r = rem & 15;
        float D = D25[k * 25 + (rem >> 4)];
        float mu = 2.0f + 1.33333333333333f * (float)r;
        float z = (D - mu) * 0.8f;
        F[k * FRS + 16 + rem] = f2bf(__expf(-z * z));
    }
    __syncthreads();

    const int lane = tid & 63;
    const int wv = tid >> 6;
    const int l15 = lane & 15;
    const int lhi = lane >> 4;

    f32x4 acc[3][2];
    #pragma unroll
    for (int mt = 0; mt < 3; ++mt)
        #pragma unroll
        for (int nn = 0; nn < 2; ++nn)
            acc[mt][nn] = (f32x4){0.f, 0.f, 0.f, 0.f};

    #pragma unroll 1
    for (int kt = 0; kt < 13; ++kt) {
        const int k0 = kt * 32 + lhi * 8;
        bf16x8 a[3], bf[2];
        #pragma unroll
        for (int mt = 0; mt < 3; ++mt)
            a[mt] = *(const bf16x8*)(F + (mt * 16 + l15) * FRS + k0);
        #pragma unroll
        for (int nn = 0; nn < 2; ++nn) {
            int n = wv * 32 + nn * 16 + l15;
            bf[nn] = *(const bf16x8*)(Wt + n * FDIM + k0);
        }
        #pragma unroll
        for (int mt = 0; mt < 3; ++mt)
            #pragma unroll
            for (int nn = 0; nn < 2; ++nn)
                acc[mt][nn] = __builtin_amdgcn_mfma_f32_16x16x32_bf16(a[mt], bf[nn], acc[mt][nn], 0, 0, 0);
    }

    __syncthreads();
    float* C = (float*)SMEM;
    #pragma unroll
    for (int mt = 0; mt < 3; ++mt) {
        #pragma unroll
        for (int nn = 0; nn < 2; ++nn) {
            int r0 = mt * 16 + lhi * 4;
            int col = wv * 32 + nn * 16 + l15;
            #pragma unroll
            for (int r = 0; r < 4; ++r)
                C[(r0 + r) * CRS + col] = acc[mt][nn][r];
        }
    }
    __syncthreads();

    const int tx = tid & 31;
    const int ty = tid >> 5;
    float g[4], be[4];
    #pragma unroll
    for (int q = 0; q < 4; ++q) {
        g[q] = gamma[tx + 32 * q];
        be[q] = beta[tx + 32 * q];
    }

    #pragma unroll
    for (int p = 0; p < 6; ++p) {
        int k = ty + 8 * p;
        float v[4];
        #pragma unroll
        for (int q = 0; q < 4; ++q)
            v[q] = C[k * CRS + tx + 32 * q];
        float s = v[0] + v[1] + v[2] + v[3];
        #pragma unroll
        for (int mo = 16; mo >= 1; mo >>= 1) s += __shfl_xor(s, mo);
        float mu = s * (1.0f / 128.0f);
        float vs = 0.0f;
        #pragma unroll
        for (int q = 0; q < 4; ++q) {
            float dv = v[q] - mu;
            vs += dv * dv;
        }
        #pragma unroll
        for (int mo = 16; mo >= 1; mo >>= 1) vs += __shfl_xor(vs, mo);
        float inv = 1.0f / sqrtf(vs * (1.0f / 128.0f) + 1e-5f);
        float* op = Eout + ((size_t)row * K_ + k) * 128;
        #pragma unroll
        for (int q = 0; q < 4; ++q)
            op[tx + 32 * q] = (v[q] - mu) * inv * g[q] + be[q];
    }
}

extern "C" void kernel_launch(void* const* d_in, const int* in_sizes, int n_in,
                              void* d_out, int out_size, void* d_ws, size_t ws_size,
                              hipStream_t stream) {
    const float* X     = (const float*)d_in[0];
    const float* mask  = (const float*)d_in[1];
    const int*   Ridx  = (const int*)d_in[2];
    const int*   chain = (const int*)d_in[3];
    const float* posW  = (const float*)d_in[4];
    const float* posb  = (const float*)d_in[5];
    const float* edgeW = (const float*)d_in[6];
    const float* gamma = (const float*)d_in[7];
    const float* beta  = (const float*)d_in[8];

    float* out   = (float*)d_out;
    float* Eout  = out;
    float* EidxF = out + (size_t)B_ * L_ * K_ * NOUT;

    float* atoms = (float*)d_ws;
    float* CaA   = atoms + (size_t)B_ * L_ * 15;
    int*   eidx  = (int*)(CaA + (size_t)B_ * L_ * 3);
    float* dnb   = (float*)(eidx + (size_t)B_ * L_ * K_);
    unsigned short* Wt = (unsigned short*)(dnb + (size_t)B_ * L_ * K_);

    hipLaunchKernelGGL(k_prepW, dim3((NOUT * FDIM + 255) / 256), dim3(256), 0, stream,
                       edgeW, Wt);
    hipLaunchKernelGGL(k_atoms, dim3((B_ * L_ + 255) / 256), dim3(256), 0, stream,
                       X, atoms, CaA);
    hipLaunchKernelGGL(k_topk, dim3(B_ * L_), dim3(256), 0, stream,
                       CaA, mask, eidx, dnb, EidxF);
    hipLaunchKernelGGL(k_edge, dim3(B_ * L_), dim3(256), 0, stream,
                       atoms, eidx, dnb, Ridx, chain, posW, posb, Wt, gamma, beta, Eout);
}

// Round 8
// 216.210 us; speedup vs baseline: 3.5156x; 1.6252x over previous
//
#include <hip/hip_runtime.h>
#include <hip/hip_bf16.h>
#include <stdint.h>
#include <math.h>

#define B_   2
#define L_   3072
#define K_   48
#define FDIM 416
#define NOUT 128
#define FRS  424   // F row stride (bf16 elems)
#define CRS  132   // C row stride (f32) for LN phase

__device__ const int PAIR_A[24] = {0,2,3,4,1,1,1,1,0,0,0,4,4,3,0,2,3,4,2,3,4,2,3,2};
__device__ const int PAIR_B[24] = {0,2,3,4,0,2,3,4,2,3,4,2,3,2,1,1,1,1,0,0,0,4,4,3};

typedef __attribute__((ext_vector_type(8))) short bf16x8;
typedef __attribute__((ext_vector_type(4))) float f32x4;

__device__ __forceinline__ unsigned short f2bf(float x) {
    unsigned int u = __float_as_uint(x);
    unsigned int r = (u + 0x7FFFu + ((u >> 16) & 1u)) >> 16;
    return (unsigned short)r;
}

// ---------------- kernel W: edgeW (416x128 f32) -> W_t (128x416 bf16) ----------------
__global__ __launch_bounds__(256) void k_prepW(const float* __restrict__ edgeW,
                                               unsigned short* __restrict__ Wt)
{
    int idx = blockIdx.x * 256 + threadIdx.x;
    if (idx >= NOUT * FDIM) return;
    int n = idx / FDIM;
    int k = idx - n * FDIM;
    Wt[idx] = f2bf(edgeW[k * NOUT + n]);
}

// ---------------- kernel A: build 5-atom frames + compact Ca ----------------
__global__ __launch_bounds__(256) void k_atoms(const float* __restrict__ X,
                                               float* __restrict__ atoms,
                                               float* __restrict__ CaA)
{
    int row = blockIdx.x * 256 + threadIdx.x;
    if (row >= B_ * L_) return;
    const float* x = X + row * 12;
    float nx = x[0], ny = x[1], nz = x[2];
    float cax = x[3], cay = x[4], caz = x[5];
    float cx = x[6], cy = x[7], cz = x[8];
    float ox = x[9], oy = x[10], oz = x[11];
    float bx = cax - nx, by = cay - ny, bz = caz - nz;
    float vx = cx - cax, vy = cy - cay, vz = cz - caz;
    float axv = by * vz - bz * vy;
    float ayv = bz * vx - bx * vz;
    float azv = bx * vy - by * vx;
    float cbx = -0.58273431f * axv + 0.56802827f * bx - 0.54067466f * vx + cax;
    float cby = -0.58273431f * ayv + 0.56802827f * by - 0.54067466f * vy + cay;
    float cbz = -0.58273431f * azv + 0.56802827f * bz - 0.54067466f * vz + caz;
    float* A = atoms + row * 15;
    A[0] = nx;  A[1] = ny;  A[2] = nz;
    A[3] = cax; A[4] = cay; A[5] = caz;
    A[6] = cx;  A[7] = cy;  A[8] = cz;
    A[9] = ox;  A[10] = oy; A[11] = oz;
    A[12] = cbx; A[13] = cby; A[14] = cbz;
    CaA[row * 3 + 0] = cax;
    CaA[row * 3 + 1] = cay;
    CaA[row * 3 + 2] = caz;
}

// ---- kernel B: per-row top-48 via radix-select + bitonic sort.
// ---- Keys: (f32(dist_f64) bits << 32) | j  -> unique, ascending (dist, j).
__global__ __launch_bounds__(256) void k_topk(const float* __restrict__ CaA,
                                              const float* __restrict__ mask,
                                              int* __restrict__ eidx,
                                              float* __restrict__ dnb,
                                              float* __restrict__ out_eidx_f)
{
    __shared__ __align__(16) unsigned long long cand[4096];  // 32 KB; first 16 KB doubles as hist
    unsigned int* hist = (unsigned int*)cand;
    __shared__ double smax[4];
    __shared__ unsigned int swave[4];
    __shared__ int sP;
    __shared__ unsigned int sCnt;

    const int row = blockIdx.x;
    const int b = row / L_;
    const int tid = threadIdx.x;
    const int lane = tid & 63;
    const int wv = tid >> 6;

    // zero histogram (covered by the dmax barrier below)
    #pragma unroll
    for (int i = 0; i < 16; ++i) hist[tid + 256 * i] = 0;
    if (tid == 0) sCnt = 0;

    const double cax = (double)CaA[row * 3 + 0];
    const double cay = (double)CaA[row * 3 + 1];
    const double caz = (double)CaA[row * 3 + 2];
    const double mi = (double)mask[row];
    const float* Cb = CaA + (size_t)b * L_ * 3;
    const float* mb = mask + (size_t)b * L_;

    double d64[12];
    float m2f[12];
    double dmax = 0.0;
    #pragma unroll
    for (int m = 0; m < 12; ++m) {
        int j = tid + 256 * m;
        double dx = cax - (double)Cb[j * 3 + 0];
        double dy = cay - (double)Cb[j * 3 + 1];
        double dz = caz - (double)Cb[j * 3 + 2];
        double s = dx * dx;
        s = s + dy * dy;
        s = s + dz * dz;
        s = s + 1e-6;
        double dist = sqrt(s);
        double m2 = mi * (double)mb[j];
        double D = m2 * dist;
        d64[m] = D;
        m2f[m] = (float)m2;
        dmax = fmax(dmax, D);
    }
    #pragma unroll
    for (int off = 32; off >= 1; off >>= 1)
        dmax = fmax(dmax, __shfl_xor(dmax, off));
    if (lane == 0) smax[wv] = dmax;
    __syncthreads();
    dmax = fmax(fmax(smax[0], smax[1]), fmax(smax[2], smax[3]));

    // keys + histogram
    unsigned long long keys[12];
    #pragma unroll
    for (int m = 0; m < 12; ++m) {
        float v = (float)(d64[m] + (1.0 - (double)m2f[m]) * dmax);
        unsigned int bits = __float_as_uint(v);
        keys[m] = ((unsigned long long)bits << 32) | (unsigned)(tid + 256 * m);
        atomicAdd(&hist[bits >> 19], 1u);
    }
    __syncthreads();

    // block scan over 4096 buckets -> find bucket P containing rank K_
    unsigned int loc[16];
    unsigned int s = 0;
    #pragma unroll
    for (int i = 0; i < 16; ++i) { loc[i] = hist[tid * 16 + i]; s += loc[i]; }
    unsigned int sc = s;
    #pragma unroll
    for (int off = 1; off < 64; off <<= 1) {
        unsigned int o = __shfl_up(sc, off);
        if (lane >= off) sc += o;
    }
    if (lane == 63) swave[wv] = sc;
    __syncthreads();
    unsigned int base = 0;
    #pragma unroll
    for (int w = 0; w < 4; ++w) if (w < wv) base += swave[w];
    unsigned int cum = base + sc - s;    // exclusive prefix before this thread's 16 buckets
    #pragma unroll
    for (int i = 0; i < 16; ++i) {
        unsigned int c = loc[i];
        if (cum < K_ && cum + c >= K_) sP = tid * 16 + i;
        cum += c;
    }
    __syncthreads();
    const unsigned int P = (unsigned int)sP;

    // compact candidates (bucket <= P); cand overlays hist (hist is dead now)
    #pragma unroll
    for (int m = 0; m < 12; ++m) {
        if ((unsigned int)(keys[m] >> 51) <= P) {
            unsigned int pos = atomicAdd(&sCnt, 1u);
            cand[pos] = keys[m];
        }
    }
    __syncthreads();
    const int cnt = (int)sCnt;
    int M2 = 64;
    while (M2 < cnt) M2 <<= 1;
    for (int i = cnt + tid; i < M2; i += 256) cand[i] = ~0ull;

    // bitonic sort ascending over M2 elements
    for (int size = 2; size <= M2; size <<= 1) {
        for (int stride = size >> 1; stride > 0; stride >>= 1) {
            __syncthreads();
            for (int i = tid; i < M2; i += 256) {
                int p = i ^ stride;
                if (p > i) {
                    unsigned long long a = cand[i];
                    unsigned long long c2 = cand[p];
                    bool up = ((i & size) == 0);
                    if ((a > c2) == up) { cand[i] = c2; cand[p] = a; }
                }
            }
        }
    }
    __syncthreads();

    if (tid < K_) {
        unsigned long long g = cand[tid];
        int gj = (int)(unsigned)(g & 0xffffffffu);
        eidx[row * K_ + tid] = gj;
        dnb[row * K_ + tid] = __uint_as_float((unsigned)(g >> 32));
        out_eidx_f[row * K_ + tid] = (float)gj;
    }
}

// ---------------- kernel C: features -> MFMA 48x416x128 -> LayerNorm ----------------
__global__ __launch_bounds__(256) void k_edge(const float* __restrict__ atoms,
                                              const int* __restrict__ eidx,
                                              const float* __restrict__ dnb,
                                              const int* __restrict__ Ridx,
                                              const int* __restrict__ chain,
                                              const float* __restrict__ posW,
                                              const float* __restrict__ posb,
                                              const unsigned short* __restrict__ Wt,
                                              const float* __restrict__ gamma,
                                              const float* __restrict__ beta,
                                              float* __restrict__ Eout)
{
    __shared__ __align__(16) unsigned short SMEM[K_ * FRS];
    __shared__ float D25[K_ * 25];
    __shared__ int sE[K_];
    __shared__ float sDnb[K_];

    const int row = blockIdx.x;
    const int b = row / L_;
    const int tid = threadIdx.x;

    if (tid < K_) {
        sE[tid] = eidx[row * K_ + tid];
        sDnb[tid] = dnb[row * K_ + tid];
    }
    __syncthreads();

    unsigned short* F = SMEM;

    for (int t = tid; t < K_ * 25; t += 256) {
        int k = t / 25, dd = t - k * 25;
        float D;
        if (dd == 0) {
            D = sDnb[k];
        } else {
            int j = sE[k];
            int ai = PAIR_A[dd - 1], bi = PAIR_B[dd - 1];
            const float* pi = atoms + ((size_t)row * 15 + ai * 3);
            const float* pj = atoms + (((size_t)b * L_ + j) * 15 + bi * 3);
            float dx = pi[0] - pj[0];
            float dy = pi[1] - pj[1];
            float dz = pi[2] - pj[2];
            float s = dx * dx;
            s += dy * dy;
            s += dz * dz;
            D = sqrtf(s + 1e-6f);
        }
        D25[t] = D;
    }

    {
        int Ri = Ridx[row];
        int ci = chain[row];
        for (int t = tid; t < K_ * 16; t += 256) {
            int k = t >> 4, r = t & 15;
            int j = sE[k];
            int off = Ri - Ridx[b * L_ + j];
            int ch = (ci == chain[b * L_ + j]) ? 1 : 0;
            int dpos = ch ? min(max(off + 32, 0), 64) : 65;
            float v = posW[dpos * 16 + r] + posb[r];
            F[k * FRS + r] = f2bf(v);
        }
    }
    __syncthreads();

    for (int t = tid; t < K_ * 400; t += 256) {
        int k = t / 400, rem = t - k * 400;
        int r = rem & 15;
        float D = D25[k * 25 + (rem >> 4)];
        float mu = 2.0f + 1.33333333333333f * (float)r;
        float z = (D - mu) * 0.8f;
        F[k * FRS + 16 + rem] = f2bf(__expf(-z * z));
    }
    __syncthreads();

    const int lane = tid & 63;
    const int wv = tid >> 6;
    const int l15 = lane & 15;
    const int lhi = lane >> 4;

    f32x4 acc[3][2];
    #pragma unroll
    for (int mt = 0; mt < 3; ++mt)
        #pragma unroll
        for (int nn = 0; nn < 2; ++nn)
            acc[mt][nn] = (f32x4){0.f, 0.f, 0.f, 0.f};

    #pragma unroll 1
    for (int kt = 0; kt < 13; ++kt) {
        const int k0 = kt * 32 + lhi * 8;
        bf16x8 a[3], bf[2];
        #pragma unroll
        for (int mt = 0; mt < 3; ++mt)
            a[mt] = *(const bf16x8*)(F + (mt * 16 + l15) * FRS + k0);
        #pragma unroll
        for (int nn = 0; nn < 2; ++nn) {
            int n = wv * 32 + nn * 16 + l15;
            bf[nn] = *(const bf16x8*)(Wt + n * FDIM + k0);
        }
        #pragma unroll
        for (int mt = 0; mt < 3; ++mt)
            #pragma unroll
            for (int nn = 0; nn < 2; ++nn)
                acc[mt][nn] = __builtin_amdgcn_mfma_f32_16x16x32_bf16(a[mt], bf[nn], acc[mt][nn], 0, 0, 0);
    }

    __syncthreads();
    float* C = (float*)SMEM;
    #pragma unroll
    for (int mt = 0; mt < 3; ++mt) {
        #pragma unroll
        for (int nn = 0; nn < 2; ++nn) {
            int r0 = mt * 16 + lhi * 4;
            int col = wv * 32 + nn * 16 + l15;
            #pragma unroll
            for (int r = 0; r < 4; ++r)
                C[(r0 + r) * CRS + col] = acc[mt][nn][r];
        }
    }
    __syncthreads();

    const int tx = tid & 31;
    const int ty = tid >> 5;
    float g[4], be[4];
    #pragma unroll
    for (int q = 0; q < 4; ++q) {
        g[q] = gamma[tx + 32 * q];
        be[q] = beta[tx + 32 * q];
    }

    #pragma unroll
    for (int p = 0; p < 6; ++p) {
        int k = ty + 8 * p;
        float v[4];
        #pragma unroll
        for (int q = 0; q < 4; ++q)
            v[q] = C[k * CRS + tx + 32 * q];
        float s = v[0] + v[1] + v[2] + v[3];
        #pragma unroll
        for (int mo = 16; mo >= 1; mo >>= 1) s += __shfl_xor(s, mo);
        float mu = s * (1.0f / 128.0f);
        float vs = 0.0f;
        #pragma unroll
        for (int q = 0; q < 4; ++q) {
            float dv = v[q] - mu;
            vs += dv * dv;
        }
        #pragma unroll
        for (int mo = 16; mo >= 1; mo >>= 1) vs += __shfl_xor(vs, mo);
        float inv = 1.0f / sqrtf(vs * (1.0f / 128.0f) + 1e-5f);
        float* op = Eout + ((size_t)row * K_ + k) * 128;
        #pragma unroll
        for (int q = 0; q < 4; ++q)
            op[tx + 32 * q] = (v[q] - mu) * inv * g[q] + be[q];
    }
}

extern "C" void kernel_launch(void* const* d_in, const int* in_sizes, int n_in,
                              void* d_out, int out_size, void* d_ws, size_t ws_size,
                              hipStream_t stream) {
    const float* X     = (const float*)d_in[0];
    const float* mask  = (const float*)d_in[1];
    const int*   Ridx  = (const int*)d_in[2];
    const int*   chain = (const int*)d_in[3];
    const float* posW  = (const float*)d_in[4];
    const float* posb  = (const float*)d_in[5];
    const float* edgeW = (const float*)d_in[6];
    const float* gamma = (const float*)d_in[7];
    const float* beta  = (const float*)d_in[8];

    float* out   = (float*)d_out;
    float* Eout  = out;
    float* EidxF = out + (size_t)B_ * L_ * K_ * NOUT;

    float* atoms = (float*)d_ws;
    float* CaA   = atoms + (size_t)B_ * L_ * 15;
    int*   eidx  = (int*)(CaA + (size_t)B_ * L_ * 3);
    float* dnb   = (float*)(eidx + (size_t)B_ * L_ * K_);
    unsigned short* Wt = (unsigned short*)(dnb + (size_t)B_ * L_ * K_);

    hipLaunchKernelGGL(k_prepW, dim3((NOUT * FDIM + 255) / 256), dim3(256), 0, stream,
                       edgeW, Wt);
    hipLaunchKernelGGL(k_atoms, dim3((B_ * L_ + 255) / 256), dim3(256), 0, stream,
                       X, atoms, CaA);
    hipLaunchKernelGGL(k_topk, dim3(B_ * L_), dim3(256), 0, stream,
                       CaA, mask, eidx, dnb, EidxF);
    hipLaunchKernelGGL(k_edge, dim3(B_ * L_), dim3(256), 0, stream,
                       atoms, eidx, dnb, Ridx, chain, posW, posb, Wt, gamma, beta, Eout);
}

// Round 9
// 166.232 us; speedup vs baseline: 4.5726x; 1.3006x over previous
//
#include <hip/hip_runtime.h>
#include <hip/hip_bf16.h>
#include <stdint.h>
#include <math.h>

#define B_   2
#define L_   3072
#define K_   48
#define FDIM 416
#define NOUT 128
#define FRS  424   // F row stride (bf16): 848B, 212dw, 212%32=20 -> conflict-free-ish b128
#define CRS  132   // C row stride (f32) for LN phase

// PAIRC[dd] = ai*8+bi for pair dd (dd = 1..24 uses PAIRC[dd-1])
__device__ const unsigned char PAIRC[24] = {
    0, 18, 27, 36, 8, 10, 11, 12, 2, 3, 4, 34, 35, 26,
    1, 17, 25, 33, 16, 24, 32, 20, 28, 19
};

typedef __attribute__((ext_vector_type(8))) short bf16x8;
typedef __attribute__((ext_vector_type(4))) float f32x4;

__device__ __forceinline__ unsigned short f2bf(float x) {
    unsigned int u = __float_as_uint(x);
    unsigned int r = (u + 0x7FFFu + ((u >> 16) & 1u)) >> 16;
    return (unsigned short)r;
}

__device__ __forceinline__ unsigned int cvtpk_bf16(float a, float b) {
    unsigned int r;
    asm("v_cvt_pk_bf16_f32 %0, %1, %2" : "=v"(r) : "v"(a), "v"(b));
    return r;   // lo = bf16(a), hi = bf16(b), RNE
}

// ---------------- kernel W: edgeW (416x128 f32) -> W_t (128x416 bf16) ----------------
__global__ __launch_bounds__(256) void k_prepW(const float* __restrict__ edgeW,
                                               unsigned short* __restrict__ Wt)
{
    int idx = blockIdx.x * 256 + threadIdx.x;
    if (idx >= NOUT * FDIM) return;
    int n = idx / FDIM;
    int k = idx - n * FDIM;
    Wt[idx] = f2bf(edgeW[k * NOUT + n]);
}

// ---------------- kernel A: build 5-atom frames (padded [16]) + compact Ca ----------------
__global__ __launch_bounds__(256) void k_atoms(const float* __restrict__ X,
                                               float* __restrict__ atoms,
                                               float* __restrict__ CaA)
{
    int row = blockIdx.x * 256 + threadIdx.x;
    if (row >= B_ * L_) return;
    const float* x = X + row * 12;
    float nx = x[0], ny = x[1], nz = x[2];
    float cax = x[3], cay = x[4], caz = x[5];
    float cx = x[6], cy = x[7], cz = x[8];
    float ox = x[9], oy = x[10], oz = x[11];
    float bx = cax - nx, by = cay - ny, bz = caz - nz;
    float vx = cx - cax, vy = cy - cay, vz = cz - caz;
    float axv = by * vz - bz * vy;
    float ayv = bz * vx - bx * vz;
    float azv = bx * vy - by * vx;
    float cbx = -0.58273431f * axv + 0.56802827f * bx - 0.54067466f * vx + cax;
    float cby = -0.58273431f * ayv + 0.56802827f * by - 0.54067466f * vy + cay;
    float cbz = -0.58273431f * azv + 0.56802827f * bz - 0.54067466f * vz + caz;
    float* A = atoms + row * 16;
    A[0] = nx;  A[1] = ny;  A[2] = nz;
    A[3] = cax; A[4] = cay; A[5] = caz;
    A[6] = cx;  A[7] = cy;  A[8] = cz;
    A[9] = ox;  A[10] = oy; A[11] = oz;
    A[12] = cbx; A[13] = cby; A[14] = cbz;
    A[15] = 0.f;
    CaA[row * 3 + 0] = cax;
    CaA[row * 3 + 1] = cay;
    CaA[row * 3 + 2] = caz;
}

// ---- kernel B: per-row top-48 via radix-select + bitonic sort. ----
__global__ __launch_bounds__(256) void k_topk(const float* __restrict__ CaA,
                                              const float* __restrict__ mask,
                                              int* __restrict__ eidx,
                                              float* __restrict__ dnb,
                                              float* __restrict__ out_eidx_f)
{
    __shared__ __align__(16) unsigned long long cand[4096];
    unsigned int* hist = (unsigned int*)cand;
    __shared__ double smax[4];
    __shared__ unsigned int swave[4];
    __shared__ int sP;
    __shared__ unsigned int sCnt;

    const int row = blockIdx.x;
    const int b = row / L_;
    const int tid = threadIdx.x;
    const int lane = tid & 63;
    const int wv = tid >> 6;

    #pragma unroll
    for (int i = 0; i < 16; ++i) hist[tid + 256 * i] = 0;
    if (tid == 0) sCnt = 0;

    const double cax = (double)CaA[row * 3 + 0];
    const double cay = (double)CaA[row * 3 + 1];
    const double caz = (double)CaA[row * 3 + 2];
    const double mi = (double)mask[row];
    const float* Cb = CaA + (size_t)b * L_ * 3;
    const float* mb = mask + (size_t)b * L_;

    double d64[12];
    float m2f[12];
    double dmax = 0.0;
    #pragma unroll
    for (int m = 0; m < 12; ++m) {
        int j = tid + 256 * m;
        double dx = cax - (double)Cb[j * 3 + 0];
        double dy = cay - (double)Cb[j * 3 + 1];
        double dz = caz - (double)Cb[j * 3 + 2];
        double s = dx * dx;
        s = s + dy * dy;
        s = s + dz * dz;
        s = s + 1e-6;
        double dist = sqrt(s);
        double m2 = mi * (double)mb[j];
        double D = m2 * dist;
        d64[m] = D;
        m2f[m] = (float)m2;
        dmax = fmax(dmax, D);
    }
    #pragma unroll
    for (int off = 32; off >= 1; off >>= 1)
        dmax = fmax(dmax, __shfl_xor(dmax, off));
    if (lane == 0) smax[wv] = dmax;
    __syncthreads();
    dmax = fmax(fmax(smax[0], smax[1]), fmax(smax[2], smax[3]));

    unsigned long long keys[12];
    #pragma unroll
    for (int m = 0; m < 12; ++m) {
        float v = (float)(d64[m] + (1.0 - (double)m2f[m]) * dmax);
        unsigned int bits = __float_as_uint(v);
        keys[m] = ((unsigned long long)bits << 32) | (unsigned)(tid + 256 * m);
        atomicAdd(&hist[bits >> 19], 1u);
    }
    __syncthreads();

    unsigned int loc[16];
    unsigned int s = 0;
    #pragma unroll
    for (int i = 0; i < 16; ++i) { loc[i] = hist[tid * 16 + i]; s += loc[i]; }
    unsigned int sc = s;
    #pragma unroll
    for (int off = 1; off < 64; off <<= 1) {
        unsigned int o = __shfl_up(sc, off);
        if (lane >= off) sc += o;
    }
    if (lane == 63) swave[wv] = sc;
    __syncthreads();
    unsigned int base = 0;
    #pragma unroll
    for (int w = 0; w < 4; ++w) if (w < wv) base += swave[w];
    unsigned int cum = base + sc - s;
    #pragma unroll
    for (int i = 0; i < 16; ++i) {
        unsigned int c = loc[i];
        if (cum < K_ && cum + c >= K_) sP = tid * 16 + i;
        cum += c;
    }
    __syncthreads();
    const unsigned int P = (unsigned int)sP;

    #pragma unroll
    for (int m = 0; m < 12; ++m) {
        if ((unsigned int)(keys[m] >> 51) <= P) {
            unsigned int pos = atomicAdd(&sCnt, 1u);
            cand[pos] = keys[m];
        }
    }
    __syncthreads();
    const int cnt = (int)sCnt;
    int M2 = 64;
    while (M2 < cnt) M2 <<= 1;
    for (int i = cnt + tid; i < M2; i += 256) cand[i] = ~0ull;

    for (int size = 2; size <= M2; size <<= 1) {
        for (int stride = size >> 1; stride > 0; stride >>= 1) {
            __syncthreads();
            for (int i = tid; i < M2; i += 256) {
                int p = i ^ stride;
                if (p > i) {
                    unsigned long long a = cand[i];
                    unsigned long long c2 = cand[p];
                    bool up = ((i & size) == 0);
                    if ((a > c2) == up) { cand[i] = c2; cand[p] = a; }
                }
            }
        }
    }
    __syncthreads();

    if (tid < K_) {
        unsigned long long g = cand[tid];
        int gj = (int)(unsigned)(g & 0xffffffffu);
        eidx[row * K_ + tid] = gj;
        dnb[row * K_ + tid] = __uint_as_float((unsigned)(g >> 32));
        out_eidx_f[row * K_ + tid] = (float)gj;
    }
}

// ---------------- kernel C: fused features -> MFMA 48x416x128 -> LayerNorm ----------------
__global__ __launch_bounds__(256) void k_edge(const float* __restrict__ atoms,
                                              const int* __restrict__ eidx,
                                              const float* __restrict__ dnb,
                                              const int* __restrict__ Ridx,
                                              const int* __restrict__ chain,
                                              const float* __restrict__ posW,
                                              const float* __restrict__ posb,
                                              const unsigned short* __restrict__ Wt,
                                              const float* __restrict__ gamma,
                                              const float* __restrict__ beta,
                                              float* __restrict__ Eout)
{
    __shared__ __align__(16) unsigned short SMEM[K_ * FRS]; // F (bf16); later C (f32 48x132) overlay
    __shared__ __align__(16) float sAtoms[K_][16];
    __shared__ __align__(16) float sOwn[16];
    __shared__ int   sE[K_];
    __shared__ float sDnb[K_];
    __shared__ int   sDpos[K_];

    const int row = blockIdx.x;
    const int b = row / L_;
    const int tid = threadIdx.x;

    if (tid < K_) {
        sE[tid] = eidx[row * K_ + tid];
        sDnb[tid] = dnb[row * K_ + tid];
    }
    __syncthreads();

    // stage neighbor atoms (coalesced float4), own atoms, dpos
    if (tid < 192) {
        int k = tid >> 2, part = tid & 3;
        const float4 v = *(const float4*)(atoms + ((size_t)b * L_ + sE[k]) * 16 + part * 4);
        *(float4*)(&sAtoms[k][part * 4]) = v;
    } else if (tid < 196) {
        int part = tid - 192;
        *(float4*)(&sOwn[part * 4]) = *(const float4*)(atoms + (size_t)row * 16 + part * 4);
    } else if (tid >= 208) {
        int k = tid - 208;
        int j = sE[k];
        int off = Ridx[row] - Ridx[b * L_ + j];
        int ch = (chain[row] == chain[b * L_ + j]) ? 1 : 0;
        sDpos[k] = ch ? min(max(off + 32, 0), 64) : 65;
    }
    __syncthreads();

    unsigned short* F = SMEM;

    // fused distance + RBF: thread -> (k, dd0), 5 dd's each, 16 RBFs per dd
    if (tid < 240) {
        const int k = tid / 5;
        const int dd0 = tid - k * 5;
        #pragma unroll
        for (int s5 = 0; s5 < 5; ++s5) {
            const int dd = dd0 + 5 * s5;
            float D;
            if (dd == 0) {
                D = sDnb[k];
            } else {
                int pr = PAIRC[dd - 1];
                int ai = pr >> 3, bi = pr & 7;
                float dx = sOwn[ai * 3 + 0] - sAtoms[k][bi * 3 + 0];
                float dy = sOwn[ai * 3 + 1] - sAtoms[k][bi * 3 + 1];
                float dz = sOwn[ai * 3 + 2] - sAtoms[k][bi * 3 + 2];
                D = sqrtf(fmaf(dz, dz, fmaf(dy, dy, dx * dx)) + 1e-6f);
            }
            // 16 RBFs, incremental z; exp(-z^2), z = (D-mu)*0.8, mu step 4/3
            float z = (D - 2.0f) * 0.8f;
            unsigned int u[8];
            #pragma unroll
            for (int p = 0; p < 8; ++p) {
                float e0 = __expf(-(z * z)); z -= 1.0666667f;
                float e1 = __expf(-(z * z)); z -= 1.0666667f;
                u[p] = cvtpk_bf16(e0, e1);
            }
            uint4* dst = (uint4*)(F + k * FRS + 16 + dd * 16);
            dst[0] = make_uint4(u[0], u[1], u[2], u[3]);
            dst[1] = make_uint4(u[4], u[5], u[6], u[7]);
        }
    }
    // positional features: F[k][0..15]
    for (int s = tid; s < K_ * 16; s += 256) {
        int k = s >> 4, r = s & 15;
        float v = posW[sDpos[k] * 16 + r] + posb[r];
        F[k * FRS + r] = f2bf(v);
    }
    __syncthreads();

    // MFMA GEMM: C[48][128] = F[48][416] @ W[416][128]
    const int lane = tid & 63;
    const int wv = tid >> 6;
    const int l15 = lane & 15;
    const int lhi = lane >> 4;

    f32x4 acc[3][2];
    #pragma unroll
    for (int mt = 0; mt < 3; ++mt)
        #pragma unroll
        for (int nn = 0; nn < 2; ++nn)
            acc[mt][nn] = (f32x4){0.f, 0.f, 0.f, 0.f};

    #pragma unroll 1
    for (int kt = 0; kt < 13; ++kt) {
        const int k0 = kt * 32 + lhi * 8;
        bf16x8 a[3], bf[2];
        #pragma unroll
        for (int mt = 0; mt < 3; ++mt)
            a[mt] = *(const bf16x8*)(F + (mt * 16 + l15) * FRS + k0);
        #pragma unroll
        for (int nn = 0; nn < 2; ++nn) {
            int n = wv * 32 + nn * 16 + l15;
            bf[nn] = *(const bf16x8*)(Wt + n * FDIM + k0);
        }
        #pragma unroll
        for (int mt = 0; mt < 3; ++mt)
            #pragma unroll
            for (int nn = 0; nn < 2; ++nn)
                acc[mt][nn] = __builtin_amdgcn_mfma_f32_16x16x32_bf16(a[mt], bf[nn], acc[mt][nn], 0, 0, 0);
    }

    __syncthreads();
    float* C = (float*)SMEM;
    #pragma unroll
    for (int mt = 0; mt < 3; ++mt) {
        #pragma unroll
        for (int nn = 0; nn < 2; ++nn) {
            int r0 = mt * 16 + lhi * 4;
            int col = wv * 32 + nn * 16 + l15;
            #pragma unroll
            for (int r = 0; r < 4; ++r)
                C[(r0 + r) * CRS + col] = acc[mt][nn][r];
        }
    }
    __syncthreads();

    const int tx = tid & 31;
    const int ty = tid >> 5;
    float g[4], be[4];
    #pragma unroll
    for (int q = 0; q < 4; ++q) {
        g[q] = gamma[tx + 32 * q];
        be[q] = beta[tx + 32 * q];
    }

    #pragma unroll
    for (int p = 0; p < 6; ++p) {
        int k = ty + 8 * p;
        float v[4];
        #pragma unroll
        for (int q = 0; q < 4; ++q)
            v[q] = C[k * CRS + tx + 32 * q];
        float s = v[0] + v[1] + v[2] + v[3];
        #pragma unroll
        for (int mo = 16; mo >= 1; mo >>= 1) s += __shfl_xor(s, mo);
        float mu = s * (1.0f / 128.0f);
        float vs = 0.0f;
        #pragma unroll
        for (int q = 0; q < 4; ++q) {
            float dv = v[q] - mu;
            vs += dv * dv;
        }
        #pragma unroll
        for (int mo = 16; mo >= 1; mo >>= 1) vs += __shfl_xor(vs, mo);
        float inv = 1.0f / sqrtf(vs * (1.0f / 128.0f) + 1e-5f);
        float* op = Eout + ((size_t)row * K_ + k) * 128;
        #pragma unroll
        for (int q = 0; q < 4; ++q)
            op[tx + 32 * q] = (v[q] - mu) * inv * g[q] + be[q];
    }
}

extern "C" void kernel_launch(void* const* d_in, const int* in_sizes, int n_in,
                              void* d_out, int out_size, void* d_ws, size_t ws_size,
                              hipStream_t stream) {
    const float* X     = (const float*)d_in[0];
    const float* mask  = (const float*)d_in[1];
    const int*   Ridx  = (const int*)d_in[2];
    const int*   chain = (const int*)d_in[3];
    const float* posW  = (const float*)d_in[4];
    const float* posb  = (const float*)d_in[5];
    const float* edgeW = (const float*)d_in[6];
    const float* gamma = (const float*)d_in[7];
    const float* beta  = (const float*)d_in[8];

    float* out   = (float*)d_out;
    float* Eout  = out;
    float* EidxF = out + (size_t)B_ * L_ * K_ * NOUT;

    float* atoms = (float*)d_ws;                                  // B*L*16
    float* CaA   = atoms + (size_t)B_ * L_ * 16;                  // B*L*3
    int*   eidx  = (int*)(CaA + (size_t)B_ * L_ * 3);             // B*L*K
    float* dnb   = (float*)(eidx + (size_t)B_ * L_ * K_);         // B*L*K
    unsigned short* Wt = (unsigned short*)(dnb + (size_t)B_ * L_ * K_);  // 128*416 bf16

    hipLaunchKernelGGL(k_prepW, dim3((NOUT * FDIM + 255) / 256), dim3(256), 0, stream,
                       edgeW, Wt);
    hipLaunchKernelGGL(k_atoms, dim3((B_ * L_ + 255) / 256), dim3(256), 0, stream,
                       X, atoms, CaA);
    hipLaunchKernelGGL(k_topk, dim3(B_ * L_), dim3(256), 0, stream,
                       CaA, mask, eidx, dnb, EidxF);
    hipLaunchKernelGGL(k_edge, dim3(B_ * L_), dim3(256), 0, stream,
                       atoms, eidx, dnb, Ridx, chain, posW, posb, Wt, gamma, beta, Eout);
}

// Round 10
// 156.815 us; speedup vs baseline: 4.8472x; 1.0601x over previous
//
#include <hip/hip_runtime.h>
#include <hip/hip_bf16.h>
#include <stdint.h>
#include <math.h>

#define B_   2
#define L_   3072
#define K_   48
#define FDIM 416
#define NOUT 128
#define FRS  424   // F row stride (bf16)
#define CRS  132   // C row stride (f32) for LN phase

// PAIRC[dd] = ai*8+bi for pair dd (dd = 1..24 uses PAIRC[dd-1])
__device__ const unsigned char PAIRC[24] = {
    0, 18, 27, 36, 8, 10, 11, 12, 2, 3, 4, 34, 35, 26,
    1, 17, 25, 33, 16, 24, 32, 20, 28, 19
};

typedef __attribute__((ext_vector_type(8))) short bf16x8;
typedef __attribute__((ext_vector_type(4))) float f32x4;

__device__ __forceinline__ unsigned short f2bf(float x) {
    unsigned int u = __float_as_uint(x);
    unsigned int r = (u + 0x7FFFu + ((u >> 16) & 1u)) >> 16;
    return (unsigned short)r;
}

__device__ __forceinline__ unsigned int cvtpk_bf16(float a, float b) {
    unsigned int r;
    asm("v_cvt_pk_bf16_f32 %0, %1, %2" : "=v"(r) : "v"(a), "v"(b));
    return r;
}

// ---------- kernel P: fused prep — Wt2 fragment-order bf16 + atom frames ----------
// Wt2[idx]: idx = (kt*8+nt)*512 + l15*32 + lhi*8 + e  <-  edgeW[(kt*32+lhi*8+e)*128 + nt*16+l15]
__global__ __launch_bounds__(256) void k_prep(const float* __restrict__ X,
                                              const float* __restrict__ edgeW,
                                              float* __restrict__ atoms,
                                              float* __restrict__ CaA,
                                              unsigned short* __restrict__ Wt2)
{
    const int bid = blockIdx.x;
    if (bid < 208) {
        int idx = bid * 256 + threadIdx.x;          // 0..53247
        int e   = idx & 7;
        int lhi = (idx >> 3) & 3;
        int l15 = (idx >> 5) & 15;
        int nt  = (idx >> 9) & 7;
        int kt  = idx >> 12;
        int k = kt * 32 + lhi * 8 + e;
        int n = nt * 16 + l15;
        Wt2[idx] = f2bf(edgeW[k * NOUT + n]);
    } else {
        int row = (bid - 208) * 256 + threadIdx.x;
        if (row >= B_ * L_) return;
        const float* x = X + row * 12;
        float nx = x[0], ny = x[1], nz = x[2];
        float cax = x[3], cay = x[4], caz = x[5];
        float cx = x[6], cy = x[7], cz = x[8];
        float ox = x[9], oy = x[10], oz = x[11];
        float bx = cax - nx, by = cay - ny, bz = caz - nz;
        float vx = cx - cax, vy = cy - cay, vz = cz - caz;
        float axv = by * vz - bz * vy;
        float ayv = bz * vx - bx * vz;
        float azv = bx * vy - by * vx;
        float cbx = -0.58273431f * axv + 0.56802827f * bx - 0.54067466f * vx + cax;
        float cby = -0.58273431f * ayv + 0.56802827f * by - 0.54067466f * vy + cay;
        float cbz = -0.58273431f * azv + 0.56802827f * bz - 0.54067466f * vz + caz;
        float* A = atoms + row * 16;
        A[0] = nx;  A[1] = ny;  A[2] = nz;
        A[3] = cax; A[4] = cay; A[5] = caz;
        A[6] = cx;  A[7] = cy;  A[8] = cz;
        A[9] = ox;  A[10] = oy; A[11] = oz;
        A[12] = cbx; A[13] = cby; A[14] = cbz;
        A[15] = 0.f;
        CaA[row * 3 + 0] = cax;
        CaA[row * 3 + 1] = cay;
        CaA[row * 3 + 2] = caz;
    }
}

// ---- kernel B: top-48. f32 bucketing (+1 slop) -> f64 exact refine of ~60
// ---- candidates -> wave-register bitonic. Keys bit-identical to passing grid.
__global__ __launch_bounds__(256) void k_topk(const float* __restrict__ CaA,
                                              const float* __restrict__ mask,
                                              int* __restrict__ eidx,
                                              float* __restrict__ dnb,
                                              float* __restrict__ out_eidx_f)
{
    __shared__ __align__(16) unsigned int SH[8192];   // 32 KB
    unsigned int* hist  = SH;                          // [0..4095]
    unsigned int* candJ = SH + 4096;                   // [4096..8191]
    unsigned long long* candK = (unsigned long long*)SH;  // overlays hist (cnt <= 2048)
    __shared__ unsigned int swave[4];
    __shared__ int sP;
    __shared__ unsigned int sCnt;

    const int row = blockIdx.x;
    const int b = row / L_;
    const int tid = threadIdx.x;
    const int lane = tid & 63;
    const int wv = tid >> 6;

    #pragma unroll
    for (int i = 0; i < 16; ++i) hist[tid + 256 * i] = 0;
    if (tid == 0) sCnt = 0;

    const float caxf = CaA[row * 3 + 0];
    const float cayf = CaA[row * 3 + 1];
    const float cazf = CaA[row * 3 + 2];
    const float mif = mask[row];
    const float* Cb = CaA + (size_t)b * L_ * 3;
    const float* mb = mask + (size_t)b * L_;
    __syncthreads();

    // phase 1: fast f32 distances -> bucket histogram
    unsigned int bits[12];
    #pragma unroll
    for (int m = 0; m < 12; ++m) {
        int j = tid + 256 * m;
        float dx = caxf - Cb[j * 3 + 0];
        float dy = cayf - Cb[j * 3 + 1];
        float dz = cazf - Cb[j * 3 + 2];
        float s = fmaf(dz, dz, fmaf(dy, dy, dx * dx)) + 1e-6f;
        float dist = sqrtf(s);
        // masked-out neighbors (or masked row) excluded: ref assigns them rank > 48
        bool live = (mif * mb[j]) != 0.0f;
        bits[m] = live ? __float_as_uint(dist) : 0x7F800000u;
        atomicAdd(&hist[bits[m] >> 19], 1u);
    }
    __syncthreads();

    // block scan over 4096 buckets -> bucket P containing rank K_
    unsigned int loc[16];
    unsigned int s = 0;
    #pragma unroll
    for (int i = 0; i < 16; ++i) { loc[i] = hist[tid * 16 + i]; s += loc[i]; }
    unsigned int sc = s;
    #pragma unroll
    for (int off = 1; off < 64; off <<= 1) {
        unsigned int o = __shfl_up(sc, off);
        if (lane >= off) sc += o;
    }
    if (lane == 63) swave[wv] = sc;
    __syncthreads();
    unsigned int base = 0;
    #pragma unroll
    for (int w = 0; w < 4; ++w) if (w < wv) base += swave[w];
    unsigned int cum = base + sc - s;
    #pragma unroll
    for (int i = 0; i < 16; ++i) {
        unsigned int c = loc[i];
        if (cum < K_ && cum + c >= K_) sP = tid * 16 + i;
        cum += c;
    }
    __syncthreads();
    const unsigned int Pth = (unsigned int)sP + 1;  // +1 bucket slop covers f32-approx error

    // compact candidate j's
    #pragma unroll
    for (int m = 0; m < 12; ++m) {
        if ((bits[m] >> 19) <= Pth) {
            unsigned int pos = atomicAdd(&sCnt, 1u);
            candJ[pos] = (unsigned)(tid + 256 * m);
        }
    }
    __syncthreads();
    int cnt = (int)sCnt;
    if (cnt > 2048) cnt = 2048;   // unreachable for real data; bounds safety

    // refine: exact f64 distance for candidates (hist region is dead -> candK overlay)
    const double cax = (double)caxf, cay = (double)cayf, caz = (double)cazf;
    for (int i = tid; i < cnt; i += 256) {
        int j = (int)candJ[i];
        double dx = cax - (double)Cb[j * 3 + 0];
        double dy = cay - (double)Cb[j * 3 + 1];
        double dz = caz - (double)Cb[j * 3 + 2];
        double ss = dx * dx;
        ss = ss + dy * dy;
        ss = ss + dz * dz;
        ss = ss + 1e-6;
        float v = (float)sqrt(ss);
        candK[i] = ((unsigned long long)__float_as_uint(v) << 32) | (unsigned)j;
    }
    __syncthreads();

    if (cnt <= 64) {
        // wave 0: register bitonic sort of 64, ascending (tie -> lower j via key low bits)
        if (wv == 0) {
            unsigned long long k = (lane < cnt) ? candK[lane] : ~0ull;
            #pragma unroll
            for (int size = 2; size <= 64; size <<= 1) {
                #pragma unroll
                for (int stride = size >> 1; stride >= 1; stride >>= 1) {
                    unsigned long long o = __shfl_xor(k, stride);
                    bool low = (lane & stride) == 0;
                    bool up = (lane & size) == 0 || size == 64;
                    unsigned long long mn = k < o ? k : o;
                    unsigned long long mx = k < o ? o : k;
                    k = (low == up) ? mn : mx;
                }
            }
            if (lane < K_) {
                int gj = (int)(unsigned)(k & 0xffffffffu);
                eidx[row * K_ + lane] = gj;
                dnb[row * K_ + lane] = __uint_as_float((unsigned)(k >> 32));
                out_eidx_f[row * K_ + lane] = (float)gj;
            }
        }
    } else {
        int M2 = 128;
        while (M2 < cnt) M2 <<= 1;
        for (int i = cnt + tid; i < M2; i += 256) candK[i] = ~0ull;
        for (int size = 2; size <= M2; size <<= 1) {
            for (int stride = size >> 1; stride > 0; stride >>= 1) {
                __syncthreads();
                for (int i = tid; i < M2; i += 256) {
                    int p = i ^ stride;
                    if (p > i) {
                        unsigned long long a = candK[i];
                        unsigned long long c2 = candK[p];
                        bool up = ((i & size) == 0);
                        if ((a > c2) == up) { candK[i] = c2; candK[p] = a; }
                    }
                }
            }
        }
        __syncthreads();
        if (tid < K_) {
            unsigned long long g = candK[tid];
            int gj = (int)(unsigned)(g & 0xffffffffu);
            eidx[row * K_ + tid] = gj;
            dnb[row * K_ + tid] = __uint_as_float((unsigned)(g >> 32));
            out_eidx_f[row * K_ + tid] = (float)gj;
        }
    }
}

// ---------------- kernel C: fused features -> MFMA 48x416x128 -> LayerNorm ----------------
__global__ __launch_bounds__(256) void k_edge(const float* __restrict__ atoms,
                                              const int* __restrict__ eidx,
                                              const float* __restrict__ dnb,
                                              const int* __restrict__ Ridx,
                                              const int* __restrict__ chain,
                                              const float* __restrict__ posW,
                                              const float* __restrict__ posb,
                                              const unsigned short* __restrict__ Wt2,
                                              const float* __restrict__ gamma,
                                              const float* __restrict__ beta,
                                              float* __restrict__ Eout)
{
    __shared__ __align__(16) unsigned short SMEM[K_ * FRS]; // F (bf16); later C (f32 48x132)
    __shared__ __align__(16) float sAtoms[K_][16];
    __shared__ __align__(16) float sOwn[16];
    __shared__ int   sE[K_];
    __shared__ float sDnb[K_];
    __shared__ int   sDpos[K_];

    const int row = blockIdx.x;
    const int b = row / L_;
    const int tid = threadIdx.x;

    if (tid < K_) {
        sE[tid] = eidx[row * K_ + tid];
        sDnb[tid] = dnb[row * K_ + tid];
    }
    __syncthreads();

    if (tid < 192) {
        int k = tid >> 2, part = tid & 3;
        const float4 v = *(const float4*)(atoms + ((size_t)b * L_ + sE[k]) * 16 + part * 4);
        *(float4*)(&sAtoms[k][part * 4]) = v;
    } else if (tid < 196) {
        int part = tid - 192;
        *(float4*)(&sOwn[part * 4]) = *(const float4*)(atoms + (size_t)row * 16 + part * 4);
    } else if (tid >= 208) {
        int k = tid - 208;
        int j = sE[k];
        int off = Ridx[row] - Ridx[b * L_ + j];
        int ch = (chain[row] == chain[b * L_ + j]) ? 1 : 0;
        sDpos[k] = ch ? min(max(off + 32, 0), 64) : 65;
    }
    __syncthreads();

    unsigned short* F = SMEM;

    if (tid < 240) {
        const int k = tid / 5;
        const int dd0 = tid - k * 5;
        #pragma unroll
        for (int s5 = 0; s5 < 5; ++s5) {
            const int dd = dd0 + 5 * s5;
            float D;
            if (dd == 0) {
                D = sDnb[k];
            } else {
                int pr = PAIRC[dd - 1];
                int ai = pr >> 3, bi = pr & 7;
                float dx = sOwn[ai * 3 + 0] - sAtoms[k][bi * 3 + 0];
                float dy = sOwn[ai * 3 + 1] - sAtoms[k][bi * 3 + 1];
                float dz = sOwn[ai * 3 + 2] - sAtoms[k][bi * 3 + 2];
                D = sqrtf(fmaf(dz, dz, fmaf(dy, dy, dx * dx)) + 1e-6f);
            }
            float z = (D - 2.0f) * 0.8f;
            unsigned int u[8];
            #pragma unroll
            for (int p = 0; p < 8; ++p) {
                float e0 = __expf(-(z * z)); z -= 1.0666667f;
                float e1 = __expf(-(z * z)); z -= 1.0666667f;
                u[p] = cvtpk_bf16(e0, e1);
            }
            uint4* dst = (uint4*)(F + k * FRS + 16 + dd * 16);
            dst[0] = make_uint4(u[0], u[1], u[2], u[3]);
            dst[1] = make_uint4(u[4], u[5], u[6], u[7]);
        }
    }
    for (int s = tid; s < K_ * 16; s += 256) {
        int k = s >> 4, r = s & 15;
        float v = posW[sDpos[k] * 16 + r] + posb[r];
        F[k * FRS + r] = f2bf(v);
    }
    __syncthreads();

    // MFMA GEMM: C[48][128] = F[48][416] @ W[416][128]; B from fragment-ordered Wt2
    const int lane = tid & 63;
    const int wv = tid >> 6;
    const int l15 = lane & 15;
    const int lhi = lane >> 4;

    f32x4 acc[3][2];
    #pragma unroll
    for (int mt = 0; mt < 3; ++mt)
        #pragma unroll
        for (int nn = 0; nn < 2; ++nn)
            acc[mt][nn] = (f32x4){0.f, 0.f, 0.f, 0.f};

    const unsigned short* wp0 = Wt2 + (wv * 2 + 0) * 512 + l15 * 32 + lhi * 8;
    const unsigned short* wp1 = wp0 + 512;

    bf16x8 bc0 = *(const bf16x8*)(wp0);
    bf16x8 bc1 = *(const bf16x8*)(wp1);

    #pragma unroll 1
    for (int kt = 0; kt < 13; ++kt) {
        bf16x8 bn0, bn1;
        if (kt < 12) {
            bn0 = *(const bf16x8*)(wp0 + (kt + 1) * 4096);
            bn1 = *(const bf16x8*)(wp1 + (kt + 1) * 4096);
        }
        const int k0 = kt * 32 + lhi * 8;
        bf16x8 a0 = *(const bf16x8*)(F + (l15) * FRS + k0);
        bf16x8 a1 = *(const bf16x8*)(F + (16 + l15) * FRS + k0);
        bf16x8 a2 = *(const bf16x8*)(F + (32 + l15) * FRS + k0);
        acc[0][0] = __builtin_amdgcn_mfma_f32_16x16x32_bf16(a0, bc0, acc[0][0], 0, 0, 0);
        acc[0][1] = __builtin_amdgcn_mfma_f32_16x16x32_bf16(a0, bc1, acc[0][1], 0, 0, 0);
        acc[1][0] = __builtin_amdgcn_mfma_f32_16x16x32_bf16(a1, bc0, acc[1][0], 0, 0, 0);
        acc[1][1] = __builtin_amdgcn_mfma_f32_16x16x32_bf16(a1, bc1, acc[1][1], 0, 0, 0);
        acc[2][0] = __builtin_amdgcn_mfma_f32_16x16x32_bf16(a2, bc0, acc[2][0], 0, 0, 0);
        acc[2][1] = __builtin_amdgcn_mfma_f32_16x16x32_bf16(a2, bc1, acc[2][1], 0, 0, 0);
        bc0 = bn0;
        bc1 = bn1;
    }

    __syncthreads();
    float* C = (float*)SMEM;
    #pragma unroll
    for (int mt = 0; mt < 3; ++mt) {
        #pragma unroll
        for (int nn = 0; nn < 2; ++nn) {
            int r0 = mt * 16 + lhi * 4;
            int col = wv * 32 + nn * 16 + l15;
            #pragma unroll
            for (int r = 0; r < 4; ++r)
                C[(r0 + r) * CRS + col] = acc[mt][nn][r];
        }
    }
    __syncthreads();

    const int tx = tid & 31;
    const int ty = tid >> 5;
    float g[4], be[4];
    #pragma unroll
    for (int q = 0; q < 4; ++q) {
        g[q] = gamma[tx + 32 * q];
        be[q] = beta[tx + 32 * q];
    }

    #pragma unroll
    for (int p = 0; p < 6; ++p) {
        int k = ty + 8 * p;
        float v[4];
        #pragma unroll
        for (int q = 0; q < 4; ++q)
            v[q] = C[k * CRS + tx + 32 * q];
        float s = v[0] + v[1] + v[2] + v[3];
        #pragma unroll
        for (int mo = 16; mo >= 1; mo >>= 1) s += __shfl_xor(s, mo);
        float mu = s * (1.0f / 128.0f);
        float vs = 0.0f;
        #pragma unroll
        for (int q = 0; q < 4; ++q) {
            float dv = v[q] - mu;
            vs += dv * dv;
        }
        #pragma unroll
        for (int mo = 16; mo >= 1; mo >>= 1) vs += __shfl_xor(vs, mo);
        float inv = 1.0f / sqrtf(vs * (1.0f / 128.0f) + 1e-5f);
        float* op = Eout + ((size_t)row * K_ + k) * 128;
        #pragma unroll
        for (int q = 0; q < 4; ++q)
            op[tx + 32 * q] = (v[q] - mu) * inv * g[q] + be[q];
    }
}

extern "C" void kernel_launch(void* const* d_in, const int* in_sizes, int n_in,
                              void* d_out, int out_size, void* d_ws, size_t ws_size,
                              hipStream_t stream) {
    const float* X     = (const float*)d_in[0];
    const float* mask  = (const float*)d_in[1];
    const int*   Ridx  = (const int*)d_in[2];
    const int*   chain = (const int*)d_in[3];
    const float* posW  = (const float*)d_in[4];
    const float* posb  = (const float*)d_in[5];
    const float* edgeW = (const float*)d_in[6];
    const float* gamma = (const float*)d_in[7];
    const float* beta  = (const float*)d_in[8];

    float* out   = (float*)d_out;
    float* Eout  = out;
    float* EidxF = out + (size_t)B_ * L_ * K_ * NOUT;

    float* atoms = (float*)d_ws;                                  // B*L*16
    float* CaA   = atoms + (size_t)B_ * L_ * 16;                  // B*L*3
    int*   eidx  = (int*)(CaA + (size_t)B_ * L_ * 3);             // B*L*K
    float* dnb   = (float*)(eidx + (size_t)B_ * L_ * K_);         // B*L*K
    unsigned short* Wt2 = (unsigned short*)(dnb + (size_t)B_ * L_ * K_);  // 13*8*512 bf16

    hipLaunchKernelGGL(k_prep, dim3(208 + (B_ * L_ + 255) / 256), dim3(256), 0, stream,
                       X, edgeW, atoms, CaA, Wt2);
    hipLaunchKernelGGL(k_topk, dim3(B_ * L_), dim3(256), 0, stream,
                       CaA, mask, eidx, dnb, EidxF);
    hipLaunchKernelGGL(k_edge, dim3(B_ * L_), dim3(256), 0, stream,
                       atoms, eidx, dnb, Ridx, chain, posW, posb, Wt2, gamma, beta, Eout);
}

// Round 11
// 138.984 us; speedup vs baseline: 5.4691x; 1.1283x over previous
//
#include <hip/hip_runtime.h>
#include <hip/hip_bf16.h>
#include <stdint.h>
#include <math.h>

#define B_   2
#define L_   3072
#define K_   48
#define FDIM 416
#define NOUT 128
#define FRS8 424   // F row stride (fp8 bytes): 8B-aligned, 106 dw, stride%32=10 -> 16 banks

// PAIRC[dd] = ai*8+bi for pair dd (dd = 1..24 uses PAIRC[dd-1])
__device__ const unsigned char PAIRC[24] = {
    0, 18, 27, 36, 8, 10, 11, 12, 2, 3, 4, 34, 35, 26,
    1, 17, 25, 33, 16, 24, 32, 20, 28, 19
};

typedef __attribute__((ext_vector_type(4))) float f32x4;

// ---------- kernel P: fused prep — Wt8 fragment-order fp8 + atom frames ----------
// Wt8 byte index: (kt*8+nt)*512 + l15*32 + lhi*8 + e  <-  edgeW[(kt*32+lhi*8+e)*128 + nt*16+l15]
__global__ __launch_bounds__(256) void k_prep(const float* __restrict__ X,
                                              const float* __restrict__ edgeW,
                                              float* __restrict__ atoms,
                                              float* __restrict__ CaA,
                                              unsigned char* __restrict__ Wt8)
{
    const int bid = blockIdx.x;
    if (bid < 52) {
        int idx4 = bid * 256 + threadIdx.x;        // dword index, 0..13311
        int b = idx4 * 4;
        int e0  = b & 7;
        int lhi = (b >> 3) & 3;
        int l15 = (b >> 5) & 15;
        int nt  = (b >> 9) & 7;
        int kt  = b >> 12;
        int n = nt * 16 + l15;
        int kbase = kt * 32 + lhi * 8 + e0;
        float v0 = edgeW[(kbase + 0) * NOUT + n];
        float v1 = edgeW[(kbase + 1) * NOUT + n];
        float v2 = edgeW[(kbase + 2) * NOUT + n];
        float v3 = edgeW[(kbase + 3) * NOUT + n];
        int w = __builtin_amdgcn_cvt_pk_fp8_f32(v0, v1, 0, false);
        w = __builtin_amdgcn_cvt_pk_fp8_f32(v2, v3, w, true);
        ((unsigned int*)Wt8)[idx4] = (unsigned int)w;
    } else {
        int row = (bid - 52) * 256 + threadIdx.x;
        if (row >= B_ * L_) return;
        const float* x = X + row * 12;
        float nx = x[0], ny = x[1], nz = x[2];
        float cax = x[3], cay = x[4], caz = x[5];
        float cx = x[6], cy = x[7], cz = x[8];
        float ox = x[9], oy = x[10], oz = x[11];
        float bx = cax - nx, by = cay - ny, bz = caz - nz;
        float vx = cx - cax, vy = cy - cay, vz = cz - caz;
        float axv = by * vz - bz * vy;
        float ayv = bz * vx - bx * vz;
        float azv = bx * vy - by * vx;
        float cbx = -0.58273431f * axv + 0.56802827f * bx - 0.54067466f * vx + cax;
        float cby = -0.58273431f * ayv + 0.56802827f * by - 0.54067466f * vy + cay;
        float cbz = -0.58273431f * azv + 0.56802827f * bz - 0.54067466f * vz + caz;
        float* A = atoms + row * 16;
        A[0] = nx;  A[1] = ny;  A[2] = nz;
        A[3] = cax; A[4] = cay; A[5] = caz;
        A[6] = cx;  A[7] = cy;  A[8] = cz;
        A[9] = ox;  A[10] = oy; A[11] = oz;
        A[12] = cbx; A[13] = cby; A[14] = cbz;
        A[15] = 0.f;
        CaA[row * 3 + 0] = cax;
        CaA[row * 3 + 1] = cay;
        CaA[row * 3 + 2] = caz;
    }
}

// ---- kernel B: top-48. f32 bucketing (2048 buckets, +2 slop) -> f64 exact
// ---- refine of ~60-150 candidates -> bitonic. Keys bit-identical to passing grid.
__global__ __launch_bounds__(256) void k_topk(const float* __restrict__ CaA,
                                              const float* __restrict__ mask,
                                              int* __restrict__ eidx,
                                              float* __restrict__ dnb,
                                              float* __restrict__ out_eidx_f)
{
    __shared__ __align__(16) unsigned int SH[3072];   // 12 KB
    unsigned int* hist  = SH;                          // [0..2047]
    unsigned int* candJ = SH + 2048;                   // [2048..3071] (cap 1024)
    unsigned long long* candK = (unsigned long long*)SH;  // overlays hist (1024 u64)
    __shared__ unsigned int swave[4];
    __shared__ int sP;
    __shared__ unsigned int sCnt;

    const int row = blockIdx.x;
    const int b = row / L_;
    const int tid = threadIdx.x;
    const int lane = tid & 63;
    const int wv = tid >> 6;

    #pragma unroll
    for (int i = 0; i < 8; ++i) hist[tid + 256 * i] = 0;
    if (tid == 0) sCnt = 0;

    const float caxf = CaA[row * 3 + 0];
    const float cayf = CaA[row * 3 + 1];
    const float cazf = CaA[row * 3 + 2];
    const float mif = mask[row];
    const float* Cb = CaA + (size_t)b * L_ * 3;
    const float* mb = mask + (size_t)b * L_;
    __syncthreads();

    // phase 1: fast f32 distances -> bucket histogram
    unsigned int bits[12];
    #pragma unroll
    for (int m = 0; m < 12; ++m) {
        int j = tid + 256 * m;
        float dx = caxf - Cb[j * 3 + 0];
        float dy = cayf - Cb[j * 3 + 1];
        float dz = cazf - Cb[j * 3 + 2];
        float s = fmaf(dz, dz, fmaf(dy, dy, dx * dx)) + 1e-6f;
        float dist = sqrtf(s);
        bool live = (mif * mb[j]) != 0.0f;
        bits[m] = live ? __float_as_uint(dist) : 0x7F800000u;
        atomicAdd(&hist[bits[m] >> 20], 1u);
    }
    __syncthreads();

    // block scan over 2048 buckets -> bucket P containing rank K_
    unsigned int loc[8];
    unsigned int s = 0;
    #pragma unroll
    for (int i = 0; i < 8; ++i) { loc[i] = hist[tid * 8 + i]; s += loc[i]; }
    unsigned int sc = s;
    #pragma unroll
    for (int off = 1; off < 64; off <<= 1) {
        unsigned int o = __shfl_up(sc, off);
        if (lane >= off) sc += o;
    }
    if (lane == 63) swave[wv] = sc;
    __syncthreads();
    unsigned int base = 0;
    #pragma unroll
    for (int w = 0; w < 4; ++w) if (w < wv) base += swave[w];
    unsigned int cum = base + sc - s;
    #pragma unroll
    for (int i = 0; i < 8; ++i) {
        unsigned int c = loc[i];
        if (cum < K_ && cum + c >= K_) sP = tid * 8 + i;
        cum += c;
    }
    __syncthreads();
    const unsigned int Pth = (unsigned int)sP + 2;  // +2 bucket slop (f32-approx proof)

    #pragma unroll
    for (int m = 0; m < 12; ++m) {
        if ((bits[m] >> 20) <= Pth) {
            unsigned int pos = atomicAdd(&sCnt, 1u);
            if (pos < 1024) candJ[pos] = (unsigned)(tid + 256 * m);
        }
    }
    __syncthreads();
    int cnt = (int)sCnt;
    if (cnt > 1024) cnt = 1024;

    // refine: exact f64 distance (hist dead -> candK overlay)
    const double cax = (double)caxf, cay = (double)cayf, caz = (double)cazf;
    for (int i = tid; i < cnt; i += 256) {
        int j = (int)candJ[i];
        double dx = cax - (double)Cb[j * 3 + 0];
        double dy = cay - (double)Cb[j * 3 + 1];
        double dz = caz - (double)Cb[j * 3 + 2];
        double ss = dx * dx;
        ss = ss + dy * dy;
        ss = ss + dz * dz;
        ss = ss + 1e-6;
        float v = (float)sqrt(ss);
        candK[i] = ((unsigned long long)__float_as_uint(v) << 32) | (unsigned)j;
    }
    __syncthreads();

    if (cnt <= 64) {
        if (wv == 0) {
            unsigned long long k = (lane < cnt) ? candK[lane] : ~0ull;
            #pragma unroll
            for (int size = 2; size <= 64; size <<= 1) {
                #pragma unroll
                for (int stride = size >> 1; stride >= 1; stride >>= 1) {
                    unsigned long long o = __shfl_xor(k, stride);
                    bool low = (lane & stride) == 0;
                    bool up = (lane & size) == 0 || size == 64;
                    unsigned long long mn = k < o ? k : o;
                    unsigned long long mx = k < o ? o : k;
                    k = (low == up) ? mn : mx;
                }
            }
            if (lane < K_) {
                int gj = (int)(unsigned)(k & 0xffffffffu);
                eidx[row * K_ + lane] = gj;
                dnb[row * K_ + lane] = __uint_as_float((unsigned)(k >> 32));
                out_eidx_f[row * K_ + lane] = (float)gj;
            }
        }
    } else {
        int M2 = 128;
        while (M2 < cnt) M2 <<= 1;
        for (int i = cnt + tid; i < M2; i += 256) candK[i] = ~0ull;
        for (int size = 2; size <= M2; size <<= 1) {
            for (int stride = size >> 1; stride > 0; stride >>= 1) {
                __syncthreads();
                for (int i = tid; i < M2; i += 256) {
                    int p = i ^ stride;
                    if (p > i) {
                        unsigned long long a = candK[i];
                        unsigned long long c2 = candK[p];
                        bool up = ((i & size) == 0);
                        if ((a > c2) == up) { candK[i] = c2; candK[p] = a; }
                    }
                }
            }
        }
        __syncthreads();
        if (tid < K_) {
            unsigned long long g = candK[tid];
            int gj = (int)(unsigned)(g & 0xffffffffu);
            eidx[row * K_ + tid] = gj;
            dnb[row * K_ + tid] = __uint_as_float((unsigned)(g >> 32));
            out_eidx_f[row * K_ + tid] = (float)gj;
        }
    }
}

// ---------------- kernel C: fp8 features -> fp8 MFMA -> register LN -> store ----------------
__global__ __launch_bounds__(256) void k_edge(const float* __restrict__ atoms,
                                              const int* __restrict__ eidx,
                                              const float* __restrict__ dnb,
                                              const int* __restrict__ Ridx,
                                              const int* __restrict__ chain,
                                              const float* __restrict__ posW,
                                              const float* __restrict__ posb,
                                              const unsigned char* __restrict__ Wt8,
                                              const float* __restrict__ gamma,
                                              const float* __restrict__ beta,
                                              float* __restrict__ Eout)
{
    __shared__ __align__(16) unsigned char F8[K_ * FRS8];   // 20,352 B
    __shared__ __align__(16) float sAtoms[K_][16];
    __shared__ __align__(16) float sOwn[16];
    __shared__ int   sE[K_];
    __shared__ float sDnb[K_];
    __shared__ int   sDpos[K_];
    __shared__ float Psum[K_][4];
    __shared__ float Psq[K_][4];

    const int row = blockIdx.x;
    const int b = row / L_;
    const int tid = threadIdx.x;

    if (tid < K_) {
        sE[tid] = eidx[row * K_ + tid];
        sDnb[tid] = dnb[row * K_ + tid];
    }
    __syncthreads();

    if (tid < 192) {
        int k = tid >> 2, part = tid & 3;
        const float4 v = *(const float4*)(atoms + ((size_t)b * L_ + sE[k]) * 16 + part * 4);
        *(float4*)(&sAtoms[k][part * 4]) = v;
    } else if (tid < 196) {
        int part = tid - 192;
        *(float4*)(&sOwn[part * 4]) = *(const float4*)(atoms + (size_t)row * 16 + part * 4);
    } else if (tid >= 208) {
        int k = tid - 208;
        int j = sE[k];
        int off = Ridx[row] - Ridx[b * L_ + j];
        int ch = (chain[row] == chain[b * L_ + j]) ? 1 : 0;
        sDpos[k] = ch ? min(max(off + 32, 0), 64) : 65;
    }
    __syncthreads();

    // fused distance + RBF -> fp8
    if (tid < 240) {
        const int k = tid / 5;
        const int dd0 = tid - k * 5;
        #pragma unroll
        for (int s5 = 0; s5 < 5; ++s5) {
            const int dd = dd0 + 5 * s5;
            float D;
            if (dd == 0) {
                D = sDnb[k];
            } else {
                int pr = PAIRC[dd - 1];
                int ai = pr >> 3, bi = pr & 7;
                float dx = sOwn[ai * 3 + 0] - sAtoms[k][bi * 3 + 0];
                float dy = sOwn[ai * 3 + 1] - sAtoms[k][bi * 3 + 1];
                float dz = sOwn[ai * 3 + 2] - sAtoms[k][bi * 3 + 2];
                D = sqrtf(fmaf(dz, dz, fmaf(dy, dy, dx * dx)) + 1e-6f);
            }
            float z = (D - 2.0f) * 0.8f;
            unsigned int u[4];
            #pragma unroll
            for (int p = 0; p < 4; ++p) {
                float e0 = __expf(-(z * z)); z -= 1.0666667f;
                float e1 = __expf(-(z * z)); z -= 1.0666667f;
                float e2 = __expf(-(z * z)); z -= 1.0666667f;
                float e3 = __expf(-(z * z)); z -= 1.0666667f;
                int w = __builtin_amdgcn_cvt_pk_fp8_f32(e0, e1, 0, false);
                w = __builtin_amdgcn_cvt_pk_fp8_f32(e2, e3, w, true);
                u[p] = (unsigned int)w;
            }
            unsigned char* dst = F8 + k * FRS8 + 16 + dd * 16;
            *(uint2*)(dst) = make_uint2(u[0], u[1]);
            *(uint2*)(dst + 8) = make_uint2(u[2], u[3]);
        }
    }
    for (int s = tid; s < K_ * 16; s += 256) {
        int k = s >> 4, r = s & 15;
        float v = posW[sDpos[k] * 16 + r] + posb[r];
        int w = __builtin_amdgcn_cvt_pk_fp8_f32(v, v, 0, false);
        F8[k * FRS8 + r] = (unsigned char)(w & 0xff);
    }
    __syncthreads();

    // fp8 MFMA GEMM: C[48][128] = F[48][416] @ W[416][128]
    const int lane = tid & 63;
    const int wv = tid >> 6;
    const int l15 = lane & 15;
    const int lhi = lane >> 4;

    f32x4 acc[3][2];
    #pragma unroll
    for (int mt = 0; mt < 3; ++mt)
        #pragma unroll
        for (int nn = 0; nn < 2; ++nn)
            acc[mt][nn] = (f32x4){0.f, 0.f, 0.f, 0.f};

    const unsigned char* wp = Wt8 + wv * 1024 + l15 * 32 + lhi * 8;
    long bc0 = *(const long*)(wp);
    long bc1 = *(const long*)(wp + 512);

    #pragma unroll 1
    for (int kt = 0; kt < 13; ++kt) {
        long bn0 = 0, bn1 = 0;
        if (kt < 12) {
            bn0 = *(const long*)(wp + (kt + 1) * 4096);
            bn1 = *(const long*)(wp + (kt + 1) * 4096 + 512);
        }
        const int k0 = kt * 32 + lhi * 8;
        long a0 = *(const long*)(F8 + (l15) * FRS8 + k0);
        long a1 = *(const long*)(F8 + (16 + l15) * FRS8 + k0);
        long a2 = *(const long*)(F8 + (32 + l15) * FRS8 + k0);
        acc[0][0] = __builtin_amdgcn_mfma_f32_16x16x32_fp8_fp8(a0, bc0, acc[0][0], 0, 0, 0);
        acc[0][1] = __builtin_amdgcn_mfma_f32_16x16x32_fp8_fp8(a0, bc1, acc[0][1], 0, 0, 0);
        acc[1][0] = __builtin_amdgcn_mfma_f32_16x16x32_fp8_fp8(a1, bc0, acc[1][0], 0, 0, 0);
        acc[1][1] = __builtin_amdgcn_mfma_f32_16x16x32_fp8_fp8(a1, bc1, acc[1][1], 0, 0, 0);
        acc[2][0] = __builtin_amdgcn_mfma_f32_16x16x32_fp8_fp8(a2, bc0, acc[2][0], 0, 0, 0);
        acc[2][1] = __builtin_amdgcn_mfma_f32_16x16x32_fp8_fp8(a2, bc1, acc[2][1], 0, 0, 0);
        bc0 = bn0;
        bc1 = bn1;
    }

    // LayerNorm from fragments: wave-local 16-lane shuffle partials -> LDS cross-wave
    #pragma unroll
    for (int mt = 0; mt < 3; ++mt) {
        #pragma unroll
        for (int r = 0; r < 4; ++r) {
            float v0 = acc[mt][0][r], v1 = acc[mt][1][r];
            float s = v0 + v1;
            float q = v0 * v0 + v1 * v1;
            #pragma unroll
            for (int off = 1; off < 16; off <<= 1) {
                s += __shfl_xor(s, off);
                q += __shfl_xor(q, off);
            }
            if (l15 == 0) {
                int er = mt * 16 + lhi * 4 + r;
                Psum[er][wv] = s;
                Psq[er][wv] = q;
            }
        }
    }
    __syncthreads();

    const int c0 = wv * 32 + l15;
    float g2[2], be2[2];
    g2[0] = gamma[c0];      g2[1] = gamma[c0 + 16];
    be2[0] = beta[c0];      be2[1] = beta[c0 + 16];

    #pragma unroll
    for (int mt = 0; mt < 3; ++mt) {
        #pragma unroll
        for (int r = 0; r < 4; ++r) {
            int er = mt * 16 + lhi * 4 + r;
            float s = Psum[er][0] + Psum[er][1] + Psum[er][2] + Psum[er][3];
            float q = Psq[er][0] + Psq[er][1] + Psq[er][2] + Psq[er][3];
            float mu = s * (1.0f / 128.0f);
            float var = q * (1.0f / 128.0f) - mu * mu;
            float inv = 1.0f / sqrtf(var + 1e-5f);
            float* op = Eout + ((size_t)row * K_ + er) * 128;
            op[c0]      = (acc[mt][0][r] - mu) * inv * g2[0] + be2[0];
            op[c0 + 16] = (acc[mt][1][r] - mu) * inv * g2[1] + be2[1];
        }
    }
}

extern "C" void kernel_launch(void* const* d_in, const int* in_sizes, int n_in,
                              void* d_out, int out_size, void* d_ws, size_t ws_size,
                              hipStream_t stream) {
    const float* X     = (const float*)d_in[0];
    const float* mask  = (const float*)d_in[1];
    const int*   Ridx  = (const int*)d_in[2];
    const int*   chain = (const int*)d_in[3];
    const float* posW  = (const float*)d_in[4];
    const float* posb  = (const float*)d_in[5];
    const float* edgeW = (const float*)d_in[6];
    const float* gamma = (const float*)d_in[7];
    const float* beta  = (const float*)d_in[8];

    float* out   = (float*)d_out;
    float* Eout  = out;
    float* EidxF = out + (size_t)B_ * L_ * K_ * NOUT;

    float* atoms = (float*)d_ws;                                  // B*L*16
    float* CaA   = atoms + (size_t)B_ * L_ * 16;                  // B*L*3
    int*   eidx  = (int*)(CaA + (size_t)B_ * L_ * 3);             // B*L*K
    float* dnb   = (float*)(eidx + (size_t)B_ * L_ * K_);         // B*L*K
    unsigned char* Wt8 = (unsigned char*)(dnb + (size_t)B_ * L_ * K_);  // 53,248 B fp8

    hipLaunchKernelGGL(k_prep, dim3(52 + (B_ * L_ + 255) / 256), dim3(256), 0, stream,
                       X, edgeW, atoms, CaA, Wt8);
    hipLaunchKernelGGL(k_topk, dim3(B_ * L_), dim3(256), 0, stream,
                       CaA, mask, eidx, dnb, EidxF);
    hipLaunchKernelGGL(k_edge, dim3(B_ * L_), dim3(256), 0, stream,
                       atoms, eidx, dnb, Ridx, chain, posW, posb, Wt8, gamma, beta, Eout);
}